// Round 2
// baseline (1146.841 us; speedup 1.0000x reference)
//
#include <hip/hip_runtime.h>

#define N_NODES 100000
#define N_EDGES 3200000
#define IN_CH 30
#define H1C 64
#define H2C 32

// ---------------- Workspace layout ----------------
// floats first (row alignment), then ints:
//  h1        float[N*64]   layer-1 output
//  y2        float[N*32]   h1 @ W2l.T (transform-before-aggregate)
//  buf_m     float[N*32]   mean1 (stride 30, lifetime: agg1->linear1) then
//                          mean2 (stride 32, lifetime: agg2->final) -- disjoint
//  deg       int[N]        degree per dst (zeroed per call)
//  rowptr    int[N]        CSR row start
//  cursor    int[N]        fill cursors (copy of rowptr)
//  sorted    int[E]        src indices sorted by dst
// total = N*(64+32+32)*4 + (3N+E)*4 = 51.2MB + 14MB = 65.2MB

// ---- 1. degree histogram: 1 thread/edge, int atomics on 400KB ----
__global__ __launch_bounds__(256) void hist_kernel(const int* __restrict__ ei,
                                                   int* __restrict__ deg) {
    int e = blockIdx.x * 256 + threadIdx.x;
    if (e < N_EDGES) atomicAdd(&deg[ei[N_EDGES + e]], 1);
}

// ---- 2. exclusive scan of deg -> rowptr (+ cursor copy). Single block, 1024 thr ----
__global__ __launch_bounds__(1024) void scan_kernel(const int* __restrict__ deg,
                                                    int* __restrict__ rowptr,
                                                    int* __restrict__ cursor) {
    __shared__ int part[1024];
    const int t = threadIdx.x;
    const int lo = t * 128;
    const int hi = min(lo + 128, N_NODES);
    int s = 0;
    for (int i = lo; i < hi; ++i) s += deg[i];
    part[t] = s;
    __syncthreads();
    // Hillis-Steele inclusive scan over 1024 partials
    for (int off = 1; off < 1024; off <<= 1) {
        int v = (t >= off) ? part[t - off] : 0;
        __syncthreads();
        part[t] += v;
        __syncthreads();
    }
    int run = (t > 0) ? part[t - 1] : 0;  // exclusive prefix of this chunk
    for (int i = lo; i < hi; ++i) {
        rowptr[i] = run;
        cursor[i] = run;
        run += deg[i];
    }
}

// ---- 3. counting-sort fill: sorted[pos] = src, pos from per-dst cursor ----
__global__ __launch_bounds__(256) void fill_kernel(const int* __restrict__ ei,
                                                   int* __restrict__ cursor,
                                                   int* __restrict__ sorted) {
    int e = blockIdx.x * 256 + threadIdx.x;
    if (e < N_EDGES) {
        int src = ei[e];
        int dst = ei[N_EDGES + e];
        int pos = atomicAdd(&cursor[dst], 1);
        sorted[pos] = src;
    }
}

// ---- 4. layer-1 mean aggregation (atomic-free): 32 lanes/node, lane=channel ----
__global__ __launch_bounds__(256) void agg1_kernel(const float* __restrict__ x,
                                                   const int* __restrict__ sorted,
                                                   const int* __restrict__ rowptr,
                                                   const int* __restrict__ deg,
                                                   float* __restrict__ mean1) {
    const int lane = threadIdx.x & 31;
    const int node = blockIdx.x * 8 + (threadIdx.x >> 5);
    if (node >= N_NODES) return;
    const int base = rowptr[node];
    const int n = deg[node];
    float acc = 0.0f;
    for (int i0 = 0; i0 < n; i0 += 32) {
        const int m = min(32, n - i0);
        int s = (i0 + lane < n) ? sorted[base + i0 + lane] : 0;  // coalesced batch
        for (int i = 0; i < m; ++i) {
            int src = __shfl(s, i, 32);                           // broadcast
            if (lane < IN_CH) acc += x[src * IN_CH + lane];       // coalesced 120B row
        }
    }
    if (lane < IN_CH)
        mean1[node * IN_CH + lane] = acc / fmaxf((float)n, 1.0f);
}

// ---- 5. layer-1 dense: h1 = relu(mean1 @ W1l.T + b1 + x @ W1r.T) ----
__global__ __launch_bounds__(256) void linear1_kernel(const float* __restrict__ x,
                                                      const float* __restrict__ mean1,
                                                      const float* __restrict__ W1l,
                                                      const float* __restrict__ W1r,
                                                      const float* __restrict__ b1,
                                                      float* __restrict__ h1) {
    __shared__ float sWl[H1C * IN_CH];
    __shared__ float sWr[H1C * IN_CH];
    __shared__ float sb[H1C];
    for (int i = threadIdx.x; i < H1C * IN_CH; i += 256) { sWl[i] = W1l[i]; sWr[i] = W1r[i]; }
    if (threadIdx.x < H1C) sb[threadIdx.x] = b1[threadIdx.x];
    __syncthreads();
    const int j = threadIdx.x & 63;
    const int node = blockIdx.x * 4 + (threadIdx.x >> 6);
    if (node >= N_NODES) return;
    float acc = sb[j];
    const float* xr = x + node * IN_CH;
    const float* mr = mean1 + node * IN_CH;
#pragma unroll
    for (int c = 0; c < IN_CH; ++c)
        acc += mr[c] * sWl[j * IN_CH + c] + xr[c] * sWr[j * IN_CH + c];
    h1[node * H1C + j] = fmaxf(acc, 0.0f);
}

// ---- 6. transform-first: y2 = h1 @ W2l.T ----
__global__ __launch_bounds__(256) void y2_kernel(const float* __restrict__ h1,
                                                 const float* __restrict__ W2l,
                                                 float* __restrict__ y2) {
    __shared__ float sW[H2C * H1C];
    for (int i = threadIdx.x; i < H2C * H1C; i += 256) sW[i] = W2l[i];
    __syncthreads();
    const int k = threadIdx.x & 31;
    const int node = blockIdx.x * 8 + (threadIdx.x >> 5);
    if (node >= N_NODES) return;
    float acc = 0.0f;
    const float* hr = h1 + node * H1C;
#pragma unroll
    for (int c = 0; c < H1C; ++c) acc += hr[c] * sW[k * H1C + c];
    y2[node * H2C + k] = acc;
}

// ---- 7. layer-2 mean aggregation (atomic-free): 32 lanes/node, lane=channel ----
__global__ __launch_bounds__(256) void agg2_kernel(const float* __restrict__ y2,
                                                   const int* __restrict__ sorted,
                                                   const int* __restrict__ rowptr,
                                                   const int* __restrict__ deg,
                                                   float* __restrict__ mean2) {
    const int lane = threadIdx.x & 31;
    const int node = blockIdx.x * 8 + (threadIdx.x >> 5);
    if (node >= N_NODES) return;
    const int base = rowptr[node];
    const int n = deg[node];
    float acc = 0.0f;
    for (int i0 = 0; i0 < n; i0 += 32) {
        const int m = min(32, n - i0);
        int s = (i0 + lane < n) ? sorted[base + i0 + lane] : 0;
        for (int i = 0; i < m; ++i) {
            int src = __shfl(s, i, 32);
            acc += y2[src * H2C + lane];  // coalesced 128B row
        }
    }
    mean2[node * H2C + lane] = acc / fmaxf((float)n, 1.0f);
}

// ---- 8. final: h2 = relu(mean2 + b2 + h1 @ W2r.T); out = h2 @ Wout + bout ----
__global__ __launch_bounds__(256) void final_kernel(const float* __restrict__ h1,
                                                    const float* __restrict__ mean2,
                                                    const float* __restrict__ W2r,
                                                    const float* __restrict__ b2,
                                                    const float* __restrict__ Wout,
                                                    const float* __restrict__ bout,
                                                    float* __restrict__ out) {
    __shared__ float sW[H2C * H1C];
    __shared__ float sb[H2C];
    __shared__ float sWo[H2C];
    for (int i = threadIdx.x; i < H2C * H1C; i += 256) sW[i] = W2r[i];
    if (threadIdx.x < H2C) { sb[threadIdx.x] = b2[threadIdx.x]; sWo[threadIdx.x] = Wout[threadIdx.x]; }
    __syncthreads();
    const int k = threadIdx.x & 31;
    const int node = blockIdx.x * 8 + (threadIdx.x >> 5);
    if (node >= N_NODES) return;
    float acc = sb[k] + mean2[node * H2C + k];
    const float* hr = h1 + node * H1C;
#pragma unroll
    for (int c = 0; c < H1C; ++c) acc += hr[c] * sW[k * H1C + c];
    float val = fmaxf(acc, 0.0f) * sWo[k];
#pragma unroll
    for (int off = 16; off > 0; off >>= 1) val += __shfl_down(val, off, 32);
    if (k == 0) out[node] = val + bout[0];
}

extern "C" void kernel_launch(void* const* d_in, const int* in_sizes, int n_in,
                              void* d_out, int out_size, void* d_ws, size_t ws_size,
                              hipStream_t stream) {
    const float* x    = (const float*)d_in[0];
    const int*   ei   = (const int*)d_in[1];
    const float* W1l  = (const float*)d_in[2];
    const float* W1r  = (const float*)d_in[3];
    const float* b1   = (const float*)d_in[4];
    const float* W2l  = (const float*)d_in[5];
    const float* W2r  = (const float*)d_in[6];
    const float* b2   = (const float*)d_in[7];
    const float* Wout = (const float*)d_in[8];
    const float* bout = (const float*)d_in[9];
    float* out = (float*)d_out;

    float* fws    = (float*)d_ws;
    float* h1     = fws;                             // N*64
    float* y2     = fws + (size_t)N_NODES * 64;      // N*32
    float* buf_m  = fws + (size_t)N_NODES * 96;      // N*32 (mean1 then mean2)
    int*   iws    = (int*)(fws + (size_t)N_NODES * 128);
    int*   deg    = iws;                             // N
    int*   rowptr = iws + N_NODES;                   // N
    int*   cursor = iws + 2 * N_NODES;               // N
    int*   sorted = iws + 3 * N_NODES;               // E

    hipMemsetAsync(deg, 0, (size_t)N_NODES * sizeof(int), stream);

    const int EB = (N_EDGES + 255) / 256;   // 12500
    const int NB8 = (N_NODES + 7) / 8;      // 12500
    const int NB4 = (N_NODES + 3) / 4;      // 25000

    hist_kernel<<<EB, 256, 0, stream>>>(ei, deg);
    scan_kernel<<<1, 1024, 0, stream>>>(deg, rowptr, cursor);
    fill_kernel<<<EB, 256, 0, stream>>>(ei, cursor, sorted);
    agg1_kernel<<<NB8, 256, 0, stream>>>(x, sorted, rowptr, deg, buf_m);
    linear1_kernel<<<NB4, 256, 0, stream>>>(x, buf_m, W1l, W1r, b1, h1);
    y2_kernel<<<NB8, 256, 0, stream>>>(h1, W2l, y2);
    agg2_kernel<<<NB8, 256, 0, stream>>>(y2, sorted, rowptr, deg, buf_m);
    final_kernel<<<NB8, 256, 0, stream>>>(h1, buf_m, W2r, b2, Wout, bout, out);
}

// Round 4
// 865.266 us; speedup vs baseline: 1.3254x; 1.3254x over previous
//
#include <hip/hip_runtime.h>

#define N_NODES 100000
#define N_EDGES 3200000
#define IN_CH 30
#define H1C 64
#define H2C 32

#define NBUK 391          // ceil(N_NODES / 256): bucket = dst >> 8
#define CHUNK 7168        // edges per binA block (stage = 56 KB LDS)

// ---------------- Workspace layout (floats) ----------------
//  x32    [0,      3.2M)   x padded to stride 32 (zeros in ch 30,31)
//  h1     [3.2M,   9.6M)   layer-1 output  -- OVERLAID with pairs (ull[E]) which
//                          dies in binB before h1 is born in lin1y2
//  y2     [9.6M,  12.8M)   h1 @ W2l.T
//  buf_m  [12.8M, 16.0M)   mean1 (stride 30) then mean2 (stride 32)
//  ints at 16.0M: deg[N], rowptr[N], gcur[512], sorted[E]
// total ~77.6 MB

// ---- 1. fused: degree histogram + pad x to stride-32 ----
__global__ __launch_bounds__(256) void histpad_kernel(const int* __restrict__ ei,
                                                      const float* __restrict__ x,
                                                      int* __restrict__ deg,
                                                      float* __restrict__ x32) {
    int i = blockIdx.x * 256 + threadIdx.x;      // exactly N_EDGES threads
    atomicAdd(&deg[ei[N_EDGES + i]], 1);
    int node = i >> 5, c = i & 31;               // N_NODES*32 == N_EDGES
    x32[i] = (c < IN_CH) ? x[node * IN_CH + c] : 0.0f;
}

// ---- 2. exclusive scan deg -> rowptr; init binA bucket cursors ----
__global__ __launch_bounds__(1024) void scan_kernel(const int* __restrict__ deg,
                                                    int* __restrict__ rowptr,
                                                    int* __restrict__ gcur) {
    __shared__ int part[1024];
    const int t = threadIdx.x;
    const int lo = t * 128;
    const int hi = min(lo + 128, N_NODES);
    int s = 0;
    for (int i = lo; i < hi; ++i) s += deg[i];
    part[t] = s;
    __syncthreads();
    for (int off = 1; off < 1024; off <<= 1) {
        int v = (t >= off) ? part[t - off] : 0;
        __syncthreads();
        part[t] += v;
        __syncthreads();
    }
    int run = (t > 0) ? part[t - 1] : 0;
    for (int i = lo; i < hi; ++i) { rowptr[i] = run; run += deg[i]; }
    __syncthreads();
    if (t < NBUK) gcur[t] = rowptr[t << 8];
}

// ---- 3. pass A: LDS-binned write of (dst,src) pairs, grouped by bucket ----
__global__ __launch_bounds__(512) void binA_kernel(const int* __restrict__ ei,
                                                   int* __restrict__ gcur,
                                                   unsigned long long* __restrict__ pairs) {
    __shared__ int hist[392];
    __shared__ int lbase[392];
    __shared__ int gbase[392];
    __shared__ int hcnt[392];
    __shared__ unsigned long long stage[CHUNK];
    const int tid = threadIdx.x;
    const int e0 = blockIdx.x * CHUNK;
    const int n = min(CHUNK, N_EDGES - e0);
    for (int i = tid; i < 392; i += 512) { hist[i] = 0; hcnt[i] = 0; }
    __syncthreads();
    for (int i = tid; i < n; i += 512)
        atomicAdd(&hist[ei[N_EDGES + e0 + i] >> 8], 1);
    __syncthreads();
    if (tid < 64) {  // wave-0 strip scan: 64 lanes x 7 buckets
        int base = tid * 7, v[7], s = 0;
#pragma unroll
        for (int k = 0; k < 7; ++k) {
            int idx = base + k;
            v[k] = (idx < NBUK) ? hist[idx] : 0;
            s += v[k];
        }
        int run = s;
#pragma unroll
        for (int off = 1; off < 64; off <<= 1) {
            int t2 = __shfl_up(run, off, 64);
            if (tid >= off) run += t2;
        }
        int excl = run - s;
#pragma unroll
        for (int k = 0; k < 7; ++k) {
            int idx = base + k;
            if (idx < NBUK) lbase[idx] = excl;
            excl += v[k];
        }
    }
    __syncthreads();
    for (int b = tid; b < NBUK; b += 512) {
        int h = hist[b];
        if (h > 0) gbase[b] = atomicAdd(&gcur[b], h);
    }
    __syncthreads();
    for (int i = tid; i < n; i += 512) {
        int s = ei[e0 + i];
        int d = ei[N_EDGES + e0 + i];
        int b = d >> 8;
        int p = lbase[b] + atomicAdd(&hcnt[b], 1);
        stage[p] = ((unsigned long long)(unsigned)d << 32) | (unsigned)s;
    }
    __syncthreads();
    for (int i = tid; i < n; i += 512) {
        unsigned long long v = stage[i];
        int d = (int)(v >> 32);
        int b = d >> 8;
        pairs[gbase[b] + (i - lbase[b])] = v;   // ~144B coalesced runs
    }
}

// ---- 4. pass B: per-bucket LDS-cursor scatter into final CSR order ----
__global__ __launch_bounds__(512) void binB_kernel(const unsigned long long* __restrict__ pairs,
                                                   const int* __restrict__ rowptr,
                                                   int* __restrict__ sorted) {
    __shared__ int cur[256];
    const int tid = threadIdx.x;
    const int dstbase = blockIdx.x << 8;
    if (tid < 256) {
        int d = dstbase + tid;
        cur[tid] = (d < N_NODES) ? rowptr[d] : 0;
    }
    __syncthreads();
    const int lo = rowptr[dstbase];
    const int hi = (dstbase + 256 < N_NODES) ? rowptr[dstbase + 256] : N_EDGES;
    for (int i = lo + tid; i < hi; i += 512) {
        unsigned long long v = pairs[i];
        int d = (int)(v >> 32);
        int s = (int)(v & 0xffffffffULL);
        int pos = atomicAdd(&cur[d & 255], 1);
        sorted[pos] = s;                         // writes confined to ~32KB window
    }
}

// ---- 5. layer-1 mean aggregation (atomic-free, aligned 128B rows) ----
// Full 32-edge chunks use a constant-bound unrolled loop -> up to 32 gathers in flight.
__global__ __launch_bounds__(256) void agg1_kernel(const float* __restrict__ x32,
                                                   const int* __restrict__ sorted,
                                                   const int* __restrict__ rowptr,
                                                   const int* __restrict__ deg,
                                                   float* __restrict__ mean1) {
    const int lane = threadIdx.x & 31;
    const int node = blockIdx.x * 8 + (threadIdx.x >> 5);
    const int base = rowptr[node];
    const int n = deg[node];
    float acc = 0.0f;
    int i0 = 0;
    for (; i0 + 32 <= n; i0 += 32) {
        int s = sorted[base + i0 + lane];
#pragma unroll
        for (int i = 0; i < 32; ++i) {
            int src = __shfl(s, i, 32);
            acc += x32[src * 32 + lane];         // pad lanes add 0
        }
    }
    const int rem = n - i0;
    if (rem > 0) {
        int s = (lane < rem) ? sorted[base + i0 + lane] : 0;
        for (int i = 0; i < rem; ++i) {
            int src = __shfl(s, i, 32);
            acc += x32[src * 32 + lane];
        }
    }
    if (lane < IN_CH)
        mean1[node * IN_CH + lane] = acc / fmaxf((float)n, 1.0f);
}

// ---- 6. fused layer-1 dense + y2 transform ----
// h1 = relu(mean1 @ W1l.T + b1 + x @ W1r.T);  y2 = h1 @ W2l.T
__global__ __launch_bounds__(256) void lin1y2_kernel(const float* __restrict__ x,
                                                     const float* __restrict__ mean1,
                                                     const float* __restrict__ W1l,
                                                     const float* __restrict__ W1r,
                                                     const float* __restrict__ b1,
                                                     const float* __restrict__ W2l,
                                                     float* __restrict__ h1,
                                                     float* __restrict__ y2) {
    __shared__ float sWl[H1C * IN_CH];
    __shared__ float sWr[H1C * IN_CH];
    __shared__ float sb[H1C];
    __shared__ float sW2[H2C * H1C];
    __shared__ float sh[4 * H1C];
    const int tid = threadIdx.x;
    for (int i = tid; i < H1C * IN_CH; i += 256) { sWl[i] = W1l[i]; sWr[i] = W1r[i]; }
    for (int i = tid; i < H2C * H1C; i += 256) sW2[i] = W2l[i];
    if (tid < H1C) sb[tid] = b1[tid];
    __syncthreads();
    const int j = tid & 63;
    const int ln = tid >> 6;
    const int node = blockIdx.x * 4 + ln;        // N_NODES % 4 == 0: no guard
    float acc = sb[j];
    const float* xr = x + node * IN_CH;
    const float* mr = mean1 + node * IN_CH;
#pragma unroll
    for (int c = 0; c < IN_CH; ++c)
        acc += mr[c] * sWl[j * IN_CH + c] + xr[c] * sWr[j * IN_CH + c];
    acc = fmaxf(acc, 0.0f);
    h1[node * H1C + j] = acc;
    sh[ln * H1C + j] = acc;
    __syncthreads();
    if (tid < 128) {
        const int k = tid & 31;
        const int n2 = blockIdx.x * 4 + (tid >> 5);
        const float* hr = &sh[(tid >> 5) * H1C];
        float a = 0.0f;
#pragma unroll
        for (int c = 0; c < H1C; ++c) a += hr[c] * sW2[k * H1C + c];
        y2[n2 * H2C + k] = a;
    }
}

// ---- 7. layer-2 mean aggregation ----
__global__ __launch_bounds__(256) void agg2_kernel(const float* __restrict__ y2,
                                                   const int* __restrict__ sorted,
                                                   const int* __restrict__ rowptr,
                                                   const int* __restrict__ deg,
                                                   float* __restrict__ mean2) {
    const int lane = threadIdx.x & 31;
    const int node = blockIdx.x * 8 + (threadIdx.x >> 5);
    const int base = rowptr[node];
    const int n = deg[node];
    float acc = 0.0f;
    int i0 = 0;
    for (; i0 + 32 <= n; i0 += 32) {
        int s = sorted[base + i0 + lane];
#pragma unroll
        for (int i = 0; i < 32; ++i) {
            int src = __shfl(s, i, 32);
            acc += y2[src * H2C + lane];
        }
    }
    const int rem = n - i0;
    if (rem > 0) {
        int s = (lane < rem) ? sorted[base + i0 + lane] : 0;
        for (int i = 0; i < rem; ++i) {
            int src = __shfl(s, i, 32);
            acc += y2[src * H2C + lane];
        }
    }
    mean2[node * H2C + lane] = acc / fmaxf((float)n, 1.0f);
}

// ---- 8. final: h2 = relu(mean2 + b2 + h1 @ W2r.T); out = h2 @ Wout + bout ----
__global__ __launch_bounds__(256) void final_kernel(const float* __restrict__ h1,
                                                    const float* __restrict__ mean2,
                                                    const float* __restrict__ W2r,
                                                    const float* __restrict__ b2,
                                                    const float* __restrict__ Wout,
                                                    const float* __restrict__ bout,
                                                    float* __restrict__ out) {
    __shared__ float sW[H2C * H1C];
    __shared__ float sb[H2C];
    __shared__ float sWo[H2C];
    for (int i = threadIdx.x; i < H2C * H1C; i += 256) sW[i] = W2r[i];
    if (threadIdx.x < H2C) { sb[threadIdx.x] = b2[threadIdx.x]; sWo[threadIdx.x] = Wout[threadIdx.x]; }
    __syncthreads();
    const int k = threadIdx.x & 31;
    const int node = blockIdx.x * 8 + (threadIdx.x >> 5);
    float acc = sb[k] + mean2[node * H2C + k];
    const float* hr = h1 + node * H1C;
#pragma unroll
    for (int c = 0; c < H1C; ++c) acc += hr[c] * sW[k * H1C + c];
    float val = fmaxf(acc, 0.0f) * sWo[k];
#pragma unroll
    for (int off = 16; off > 0; off >>= 1) val += __shfl_down(val, off, 32);
    if (k == 0) out[node] = val + bout[0];
}

extern "C" void kernel_launch(void* const* d_in, const int* in_sizes, int n_in,
                              void* d_out, int out_size, void* d_ws, size_t ws_size,
                              hipStream_t stream) {
    const float* x    = (const float*)d_in[0];
    const int*   ei   = (const int*)d_in[1];
    const float* W1l  = (const float*)d_in[2];
    const float* W1r  = (const float*)d_in[3];
    const float* b1   = (const float*)d_in[4];
    const float* W2l  = (const float*)d_in[5];
    const float* W2r  = (const float*)d_in[6];
    const float* b2   = (const float*)d_in[7];
    const float* Wout = (const float*)d_in[8];
    const float* bout = (const float*)d_in[9];
    float* out = (float*)d_out;

    float* fws = (float*)d_ws;
    float* x32   = fws;                                  // N*32
    float* h1    = fws + (size_t)N_NODES * 32;           // N*64 (overlay: pairs)
    float* y2    = fws + (size_t)N_NODES * 96;           // N*32
    float* buf_m = fws + (size_t)N_NODES * 128;          // N*32
    unsigned long long* pairs = (unsigned long long*)h1; // ull[E] == N*64 floats
    int* iws    = (int*)(fws + (size_t)N_NODES * 160);
    int* deg    = iws;                                   // N
    int* rowptr = iws + N_NODES;                         // N
    int* gcur   = iws + 2 * N_NODES;                     // 512
    int* sorted = iws + 2 * N_NODES + 512;               // E

    hipMemsetAsync(deg, 0, (size_t)N_NODES * sizeof(int), stream);

    const int GA = (N_EDGES + CHUNK - 1) / CHUNK;  // 447

    histpad_kernel<<<N_EDGES / 256, 256, 0, stream>>>(ei, x, deg, x32);
    scan_kernel<<<1, 1024, 0, stream>>>(deg, rowptr, gcur);
    binA_kernel<<<GA, 512, 0, stream>>>(ei, gcur, pairs);
    binB_kernel<<<NBUK, 512, 0, stream>>>(pairs, rowptr, sorted);
    agg1_kernel<<<N_NODES / 8, 256, 0, stream>>>(x32, sorted, rowptr, deg, buf_m);
    lin1y2_kernel<<<N_NODES / 4, 256, 0, stream>>>(x, buf_m, W1l, W1r, b1, W2l, h1, y2);
    agg2_kernel<<<N_NODES / 8, 256, 0, stream>>>(y2, sorted, rowptr, deg, buf_m);
    final_kernel<<<N_NODES / 8, 256, 0, stream>>>(h1, buf_m, W2r, b2, Wout, bout, out);
}

// Round 8
// 669.717 us; speedup vs baseline: 1.7124x; 1.2920x over previous
//
#include <hip/hip_runtime.h>

#define N_NODES 100000
#define N_EDGES 3200000
#define IN_CH 30
#define H1C 64
#define H2C 32

#define NBUK 391          // ceil(N_NODES / 256): bucket = dst >> 8
#define CHUNK 7168        // edges per binA block (stage = 56 KB LDS)
#define SCAN_B 98         // ceil(N_NODES / 1024) scan blocks

// ---------------- Workspace layout (floats) ----------------
//  x32    [0,      3.2M)   x padded to stride 32 (zeros in ch 30,31)
//  h1     [3.2M,   9.6M)   layer-1 output  -- OVERLAID with pairs (ull[E]) which
//                          dies in binB before h1 is born in lin1y2
//  y2     [9.6M,  12.8M)   h1 @ W2l.T
//  buf_m  [12.8M, 16.0M)   mean1 (stride 30; only layer-1 now)
//  ints at 16.0M: deg[N], rowptr[N], gcur[512], bsum[128], boff[128], sorted[E]
// total ~77.6 MB

// ---- 1. fused: degree histogram + pad x to stride-32 ----
__global__ __launch_bounds__(256) void histpad_kernel(const int* __restrict__ ei,
                                                      const float* __restrict__ x,
                                                      int* __restrict__ deg,
                                                      float* __restrict__ x32) {
    int i = blockIdx.x * 256 + threadIdx.x;      // exactly N_EDGES threads
    atomicAdd(&deg[ei[N_EDGES + i]], 1);
    int node = i >> 5, c = i & 31;               // N_NODES*32 == N_EDGES
    x32[i] = (c < IN_CH) ? x[node * IN_CH + c] : 0.0f;
}

// ---- 2a. per-block scan: local-exclusive rowptr + block sums ----
__global__ __launch_bounds__(1024) void scanA_kernel(const int* __restrict__ deg,
                                                     int* __restrict__ rowptr,
                                                     int* __restrict__ bsum) {
    __shared__ int wsum[16];
    const int t = threadIdx.x;
    const int i = blockIdx.x * 1024 + t;
    const int lane = t & 63;
    const int wid = t >> 6;
    int v = (i < N_NODES) ? deg[i] : 0;
    int run = v;                                  // inclusive wave scan
#pragma unroll
    for (int off = 1; off < 64; off <<= 1) {
        int u = __shfl_up(run, off, 64);
        if (lane >= off) run += u;
    }
    if (lane == 63) wsum[wid] = run;
    __syncthreads();
    if (t < 16) {                                 // scan the 16 wave sums
        int w = wsum[t];
        int r2 = w;
#pragma unroll
        for (int off = 1; off < 16; off <<= 1) {
            int u = __shfl_up(r2, off, 16);
            if (t >= off) r2 += u;
        }
        wsum[t] = r2 - w;                         // exclusive
        if (t == 15) bsum[blockIdx.x] = r2;       // block total
    }
    __syncthreads();
    if (i < N_NODES) rowptr[i] = run - v + wsum[wid];
}

// ---- 2b. scan the 98 block sums (exclusive) ----
__global__ __launch_bounds__(128) void scanB_kernel(const int* __restrict__ bsum,
                                                    int* __restrict__ boff) {
    __shared__ int ws[2];
    const int t = threadIdx.x;
    int v = (t < SCAN_B) ? bsum[t] : 0;
    int run = v;
#pragma unroll
    for (int off = 1; off < 64; off <<= 1) {
        int u = __shfl_up(run, off, 64);
        if ((t & 63) >= off) run += u;
    }
    if ((t & 63) == 63) ws[t >> 6] = run;
    __syncthreads();
    int excl = run - v + ((t >= 64) ? ws[0] : 0);
    if (t < SCAN_B) boff[t] = excl;
}

// ---- 2c. add block offsets; init binA bucket cursors from final rowptr ----
__global__ __launch_bounds__(1024) void scanC_kernel(int* __restrict__ rowptr,
                                                     const int* __restrict__ boff,
                                                     int* __restrict__ gcur) {
    const int i = blockIdx.x * 1024 + threadIdx.x;
    if (i < N_NODES) {
        int r = rowptr[i] + boff[blockIdx.x];
        rowptr[i] = r;
        if ((i & 255) == 0) gcur[i >> 8] = r;
    }
}

// ---- 3. pass A: LDS-binned write of (dst,src) pairs, grouped by bucket ----
__global__ __launch_bounds__(512) void binA_kernel(const int* __restrict__ ei,
                                                   int* __restrict__ gcur,
                                                   unsigned long long* __restrict__ pairs) {
    __shared__ int hist[392];
    __shared__ int lbase[392];
    __shared__ int gbase[392];
    __shared__ int hcnt[392];
    __shared__ unsigned long long stage[CHUNK];
    const int tid = threadIdx.x;
    const int e0 = blockIdx.x * CHUNK;
    const int n = min(CHUNK, N_EDGES - e0);
    for (int i = tid; i < 392; i += 512) { hist[i] = 0; hcnt[i] = 0; }
    __syncthreads();
    for (int i = tid; i < n; i += 512)
        atomicAdd(&hist[ei[N_EDGES + e0 + i] >> 8], 1);
    __syncthreads();
    if (tid < 64) {  // wave-0 strip scan: 64 lanes x 7 buckets
        int base = tid * 7, v[7], s = 0;
#pragma unroll
        for (int k = 0; k < 7; ++k) {
            int idx = base + k;
            v[k] = (idx < NBUK) ? hist[idx] : 0;
            s += v[k];
        }
        int run = s;
#pragma unroll
        for (int off = 1; off < 64; off <<= 1) {
            int t2 = __shfl_up(run, off, 64);
            if (tid >= off) run += t2;
        }
        int excl = run - s;
#pragma unroll
        for (int k = 0; k < 7; ++k) {
            int idx = base + k;
            if (idx < NBUK) lbase[idx] = excl;
            excl += v[k];
        }
    }
    __syncthreads();
    for (int b = tid; b < NBUK; b += 512) {
        int h = hist[b];
        if (h > 0) gbase[b] = atomicAdd(&gcur[b], h);
    }
    __syncthreads();
    for (int i = tid; i < n; i += 512) {
        int s = ei[e0 + i];
        int d = ei[N_EDGES + e0 + i];
        int b = d >> 8;
        int p = lbase[b] + atomicAdd(&hcnt[b], 1);
        stage[p] = ((unsigned long long)(unsigned)d << 32) | (unsigned)s;
    }
    __syncthreads();
    for (int i = tid; i < n; i += 512) {
        unsigned long long v = stage[i];
        int d = (int)(v >> 32);
        int b = d >> 8;
        pairs[gbase[b] + (i - lbase[b])] = v;   // ~144B coalesced runs
    }
}

// ---- 4. pass B: per-bucket LDS-cursor scatter into final CSR order ----
__global__ __launch_bounds__(512) void binB_kernel(const unsigned long long* __restrict__ pairs,
                                                   const int* __restrict__ rowptr,
                                                   int* __restrict__ sorted) {
    __shared__ int cur[256];
    const int tid = threadIdx.x;
    const int dstbase = blockIdx.x << 8;
    if (tid < 256) {
        int d = dstbase + tid;
        cur[tid] = (d < N_NODES) ? rowptr[d] : 0;
    }
    __syncthreads();
    const int lo = rowptr[dstbase];
    const int hi = (dstbase + 256 < N_NODES) ? rowptr[dstbase + 256] : N_EDGES;
    for (int i = lo + tid; i < hi; i += 512) {
        unsigned long long v = pairs[i];
        int d = (int)(v >> 32);
        int s = (int)(v & 0xffffffffULL);
        int pos = atomicAdd(&cur[d & 255], 1);
        sorted[pos] = s;                         // writes confined to ~32KB window
    }
}

// ---- 5. layer-1 mean aggregation (atomic-free, aligned 128B rows) ----
// Full 32-edge chunks use a constant-bound unrolled loop -> up to 32 gathers in flight.
__global__ __launch_bounds__(256) void agg1_kernel(const float* __restrict__ x32,
                                                   const int* __restrict__ sorted,
                                                   const int* __restrict__ rowptr,
                                                   const int* __restrict__ deg,
                                                   float* __restrict__ mean1) {
    const int lane = threadIdx.x & 31;
    const int node = blockIdx.x * 8 + (threadIdx.x >> 5);
    const int base = rowptr[node];
    const int n = deg[node];
    float acc = 0.0f;
    int i0 = 0;
    for (; i0 + 32 <= n; i0 += 32) {
        int s = sorted[base + i0 + lane];
#pragma unroll
        for (int i = 0; i < 32; ++i) {
            int src = __shfl(s, i, 32);
            acc += x32[src * 32 + lane];         // pad lanes add 0
        }
    }
    const int rem = n - i0;
    if (rem > 0) {
        int s = (lane < rem) ? sorted[base + i0 + lane] : 0;
        for (int i = 0; i < rem; ++i) {
            int src = __shfl(s, i, 32);
            acc += x32[src * 32 + lane];
        }
    }
    if (lane < IN_CH)
        mean1[node * IN_CH + lane] = acc / fmaxf((float)n, 1.0f);
}

// ---- 6. fused layer-1 dense + y2 transform ----
// h1 = relu(mean1 @ W1l.T + b1 + x @ W1r.T);  y2 = h1 @ W2l.T
__global__ __launch_bounds__(256) void lin1y2_kernel(const float* __restrict__ x,
                                                     const float* __restrict__ mean1,
                                                     const float* __restrict__ W1l,
                                                     const float* __restrict__ W1r,
                                                     const float* __restrict__ b1,
                                                     const float* __restrict__ W2l,
                                                     float* __restrict__ h1,
                                                     float* __restrict__ y2) {
    __shared__ float sWl[H1C * IN_CH];
    __shared__ float sWr[H1C * IN_CH];
    __shared__ float sb[H1C];
    __shared__ float sW2[H2C * H1C];
    __shared__ float sh[4 * H1C];
    const int tid = threadIdx.x;
    for (int i = tid; i < H1C * IN_CH; i += 256) { sWl[i] = W1l[i]; sWr[i] = W1r[i]; }
    for (int i = tid; i < H2C * H1C; i += 256) sW2[i] = W2l[i];
    if (tid < H1C) sb[tid] = b1[tid];
    __syncthreads();
    const int j = tid & 63;
    const int ln = tid >> 6;
    const int node = blockIdx.x * 4 + ln;        // N_NODES % 4 == 0: no guard
    float acc = sb[j];
    const float* xr = x + node * IN_CH;
    const float* mr = mean1 + node * IN_CH;
#pragma unroll
    for (int c = 0; c < IN_CH; ++c)
        acc += mr[c] * sWl[j * IN_CH + c] + xr[c] * sWr[j * IN_CH + c];
    acc = fmaxf(acc, 0.0f);
    h1[node * H1C + j] = acc;
    sh[ln * H1C + j] = acc;
    __syncthreads();
    if (tid < 128) {
        const int k = tid & 31;
        const int n2 = blockIdx.x * 4 + (tid >> 5);
        const float* hr = &sh[(tid >> 5) * H1C];
        float a = 0.0f;
#pragma unroll
        for (int c = 0; c < H1C; ++c) a += hr[c] * sW2[k * H1C + c];
        y2[n2 * H2C + k] = a;
    }
}

// ---- 7. fused layer-2 aggregation + final head ----
// mean2 (in registers) -> h2 = relu(mean2 + b2 + h1 @ W2r.T) -> out = h2 @ Wout + bout
__global__ __launch_bounds__(256) void aggfinal_kernel(const float* __restrict__ y2,
                                                       const int* __restrict__ sorted,
                                                       const int* __restrict__ rowptr,
                                                       const int* __restrict__ deg,
                                                       const float* __restrict__ h1,
                                                       const float* __restrict__ W2r,
                                                       const float* __restrict__ b2,
                                                       const float* __restrict__ Wout,
                                                       const float* __restrict__ bout,
                                                       float* __restrict__ out) {
    __shared__ float sW[H2C * H1C];
    __shared__ float sb[H2C];
    __shared__ float sWo[H2C];
    for (int i = threadIdx.x; i < H2C * H1C; i += 256) sW[i] = W2r[i];
    if (threadIdx.x < H2C) { sb[threadIdx.x] = b2[threadIdx.x]; sWo[threadIdx.x] = Wout[threadIdx.x]; }
    __syncthreads();
    const int k = threadIdx.x & 31;
    const int node = blockIdx.x * 8 + (threadIdx.x >> 5);
    const int base = rowptr[node];
    const int n = deg[node];
    float macc = 0.0f;
    int i0 = 0;
    for (; i0 + 32 <= n; i0 += 32) {
        int s = sorted[base + i0 + k];
#pragma unroll
        for (int i = 0; i < 32; ++i) {
            int src = __shfl(s, i, 32);
            macc += y2[src * H2C + k];
        }
    }
    const int rem = n - i0;
    if (rem > 0) {
        int s = (k < rem) ? sorted[base + i0 + k] : 0;
        for (int i = 0; i < rem; ++i) {
            int src = __shfl(s, i, 32);
            macc += y2[src * H2C + k];
        }
    }
    float acc = sb[k] + macc / fmaxf((float)n, 1.0f);
    const float* hr = h1 + node * H1C;
#pragma unroll
    for (int c = 0; c < H1C; ++c) acc += hr[c] * sW[k * H1C + c];
    float val = fmaxf(acc, 0.0f) * sWo[k];
#pragma unroll
    for (int off = 16; off > 0; off >>= 1) val += __shfl_down(val, off, 32);
    if (k == 0) out[node] = val + bout[0];
}

extern "C" void kernel_launch(void* const* d_in, const int* in_sizes, int n_in,
                              void* d_out, int out_size, void* d_ws, size_t ws_size,
                              hipStream_t stream) {
    const float* x    = (const float*)d_in[0];
    const int*   ei   = (const int*)d_in[1];
    const float* W1l  = (const float*)d_in[2];
    const float* W1r  = (const float*)d_in[3];
    const float* b1   = (const float*)d_in[4];
    const float* W2l  = (const float*)d_in[5];
    const float* W2r  = (const float*)d_in[6];
    const float* b2   = (const float*)d_in[7];
    const float* Wout = (const float*)d_in[8];
    const float* bout = (const float*)d_in[9];
    float* out = (float*)d_out;

    float* fws = (float*)d_ws;
    float* x32   = fws;                                  // N*32
    float* h1    = fws + (size_t)N_NODES * 32;           // N*64 (overlay: pairs)
    float* y2    = fws + (size_t)N_NODES * 96;           // N*32
    float* buf_m = fws + (size_t)N_NODES * 128;          // N*32 (mean1)
    unsigned long long* pairs = (unsigned long long*)h1; // ull[E] == N*64 floats
    int* iws    = (int*)(fws + (size_t)N_NODES * 160);
    int* deg    = iws;                                   // N
    int* rowptr = iws + N_NODES;                         // N
    int* gcur   = iws + 2 * N_NODES;                     // 512
    int* bsum   = iws + 2 * N_NODES + 512;               // 128
    int* boff   = iws + 2 * N_NODES + 640;               // 128
    int* sorted = iws + 2 * N_NODES + 768;               // E

    hipMemsetAsync(deg, 0, (size_t)N_NODES * sizeof(int), stream);

    const int GA = (N_EDGES + CHUNK - 1) / CHUNK;  // 447

    histpad_kernel<<<N_EDGES / 256, 256, 0, stream>>>(ei, x, deg, x32);
    scanA_kernel<<<SCAN_B, 1024, 0, stream>>>(deg, rowptr, bsum);
    scanB_kernel<<<1, 128, 0, stream>>>(bsum, boff);
    scanC_kernel<<<SCAN_B, 1024, 0, stream>>>(rowptr, boff, gcur);
    binA_kernel<<<GA, 512, 0, stream>>>(ei, gcur, pairs);
    binB_kernel<<<NBUK, 512, 0, stream>>>(pairs, rowptr, sorted);
    agg1_kernel<<<N_NODES / 8, 256, 0, stream>>>(x32, sorted, rowptr, deg, buf_m);
    lin1y2_kernel<<<N_NODES / 4, 256, 0, stream>>>(x, buf_m, W1l, W1r, b1, W2l, h1, y2);
    aggfinal_kernel<<<N_NODES / 8, 256, 0, stream>>>(y2, sorted, rowptr, deg, h1,
                                                     W2r, b2, Wout, bout, out);
}

// Round 9
// 564.930 us; speedup vs baseline: 2.0301x; 1.1855x over previous
//
#include <hip/hip_runtime.h>

#define N_NODES 100000
#define N_EDGES 3200000
#define IN_CH 30
#define H1C 64
#define H2C 32

#define NBUK 391          // ceil(N_NODES / 256): bucket = dst >> 8
#define CHUNK 7168        // edges per binA block (stage = 56 KB LDS)
#define SCAN_B 98         // ceil(N_NODES / 1024) scan blocks

// ---------------- Workspace layout (floats) ----------------
//  x32    [0,      3.2M)   x padded to stride 32 (zeros in ch 30,31)
//  h1     [3.2M,   9.6M)   layer-1 output  -- OVERLAID with pairs (ull[E]) which
//                          dies in binB before h1 is born in lin1y2
//  y2     [9.6M,  12.8M)   h1 @ W2l.T
//  buf_m  [12.8M, 16.0M)   mean1 (stride 30)
//  ints at 16.0M: deg[N], rowptr[N], gcur[512], bsum[128], boff[128], sorted[E]

// ---- 1. fused: degree histogram + pad x to stride-32 ----
__global__ __launch_bounds__(256) void histpad_kernel(const int* __restrict__ ei,
                                                      const float* __restrict__ x,
                                                      int* __restrict__ deg,
                                                      float* __restrict__ x32) {
    int i = blockIdx.x * 256 + threadIdx.x;      // exactly N_EDGES threads
    atomicAdd(&deg[ei[N_EDGES + i]], 1);
    int node = i >> 5, c = i & 31;               // N_NODES*32 == N_EDGES
    x32[i] = (c < IN_CH) ? x[node * IN_CH + c] : 0.0f;
}

// ---- 2a. per-block scan: local-exclusive rowptr + block sums ----
__global__ __launch_bounds__(1024) void scanA_kernel(const int* __restrict__ deg,
                                                     int* __restrict__ rowptr,
                                                     int* __restrict__ bsum) {
    __shared__ int wsum[16];
    const int t = threadIdx.x;
    const int i = blockIdx.x * 1024 + t;
    const int lane = t & 63;
    const int wid = t >> 6;
    int v = (i < N_NODES) ? deg[i] : 0;
    int run = v;                                  // inclusive wave scan
#pragma unroll
    for (int off = 1; off < 64; off <<= 1) {
        int u = __shfl_up(run, off, 64);
        if (lane >= off) run += u;
    }
    if (lane == 63) wsum[wid] = run;
    __syncthreads();
    if (t < 16) {                                 // scan the 16 wave sums
        int w = wsum[t];
        int r2 = w;
#pragma unroll
        for (int off = 1; off < 16; off <<= 1) {
            int u = __shfl_up(r2, off, 16);
            if (t >= off) r2 += u;
        }
        wsum[t] = r2 - w;                         // exclusive
        if (t == 15) bsum[blockIdx.x] = r2;       // block total
    }
    __syncthreads();
    if (i < N_NODES) rowptr[i] = run - v + wsum[wid];
}

// ---- 2b. scan the 98 block sums (exclusive) ----
__global__ __launch_bounds__(128) void scanB_kernel(const int* __restrict__ bsum,
                                                    int* __restrict__ boff) {
    __shared__ int ws[2];
    const int t = threadIdx.x;
    int v = (t < SCAN_B) ? bsum[t] : 0;
    int run = v;
#pragma unroll
    for (int off = 1; off < 64; off <<= 1) {
        int u = __shfl_up(run, off, 64);
        if ((t & 63) >= off) run += u;
    }
    if ((t & 63) == 63) ws[t >> 6] = run;
    __syncthreads();
    int excl = run - v + ((t >= 64) ? ws[0] : 0);
    if (t < SCAN_B) boff[t] = excl;
}

// ---- 2c. add block offsets; init binA bucket cursors from final rowptr ----
__global__ __launch_bounds__(1024) void scanC_kernel(int* __restrict__ rowptr,
                                                     const int* __restrict__ boff,
                                                     int* __restrict__ gcur) {
    const int i = blockIdx.x * 1024 + threadIdx.x;
    if (i < N_NODES) {
        int r = rowptr[i] + boff[blockIdx.x];
        rowptr[i] = r;
        if ((i & 255) == 0) gcur[i >> 8] = r;
    }
}

// ---- 3. pass A: LDS-binned write of (dst,src) pairs, grouped by bucket ----
__global__ __launch_bounds__(512) void binA_kernel(const int* __restrict__ ei,
                                                   int* __restrict__ gcur,
                                                   unsigned long long* __restrict__ pairs) {
    __shared__ int hist[392];
    __shared__ int lbase[392];
    __shared__ int gbase[392];
    __shared__ int hcnt[392];
    __shared__ unsigned long long stage[CHUNK];
    const int tid = threadIdx.x;
    const int e0 = blockIdx.x * CHUNK;
    const int n = min(CHUNK, N_EDGES - e0);
    for (int i = tid; i < 392; i += 512) { hist[i] = 0; hcnt[i] = 0; }
    __syncthreads();
    for (int i = tid; i < n; i += 512)
        atomicAdd(&hist[ei[N_EDGES + e0 + i] >> 8], 1);
    __syncthreads();
    if (tid < 64) {  // wave-0 strip scan: 64 lanes x 7 buckets
        int base = tid * 7, v[7], s = 0;
#pragma unroll
        for (int k = 0; k < 7; ++k) {
            int idx = base + k;
            v[k] = (idx < NBUK) ? hist[idx] : 0;
            s += v[k];
        }
        int run = s;
#pragma unroll
        for (int off = 1; off < 64; off <<= 1) {
            int t2 = __shfl_up(run, off, 64);
            if (tid >= off) run += t2;
        }
        int excl = run - s;
#pragma unroll
        for (int k = 0; k < 7; ++k) {
            int idx = base + k;
            if (idx < NBUK) lbase[idx] = excl;
            excl += v[k];
        }
    }
    __syncthreads();
    for (int b = tid; b < NBUK; b += 512) {
        int h = hist[b];
        if (h > 0) gbase[b] = atomicAdd(&gcur[b], h);
    }
    __syncthreads();
    for (int i = tid; i < n; i += 512) {
        int s = ei[e0 + i];
        int d = ei[N_EDGES + e0 + i];
        int b = d >> 8;
        int p = lbase[b] + atomicAdd(&hcnt[b], 1);
        stage[p] = ((unsigned long long)(unsigned)d << 32) | (unsigned)s;
    }
    __syncthreads();
    for (int i = tid; i < n; i += 512) {
        unsigned long long v = stage[i];
        int d = (int)(v >> 32);
        int b = d >> 8;
        pairs[gbase[b] + (i - lbase[b])] = v;   // ~144B coalesced runs
    }
}

// ---- 4. pass B: per-bucket LDS-cursor scatter into final CSR order ----
__global__ __launch_bounds__(512) void binB_kernel(const unsigned long long* __restrict__ pairs,
                                                   const int* __restrict__ rowptr,
                                                   int* __restrict__ sorted) {
    __shared__ int cur[256];
    const int tid = threadIdx.x;
    const int dstbase = blockIdx.x << 8;
    if (tid < 256) {
        int d = dstbase + tid;
        cur[tid] = (d < N_NODES) ? rowptr[d] : 0;
    }
    __syncthreads();
    const int lo = rowptr[dstbase];
    const int hi = (dstbase + 256 < N_NODES) ? rowptr[dstbase + 256] : N_EDGES;
    for (int i = lo + tid; i < hi; i += 512) {
        unsigned long long v = pairs[i];
        int d = (int)(v >> 32);
        int s = (int)(v & 0xffffffffULL);
        int pos = atomicAdd(&cur[d & 255], 1);
        sorted[pos] = s;                         // writes confined to ~32KB window
    }
}

// ---- 5. layer-1 mean aggregation: float4 gather, 4 edge-rows per instruction ----
// lane k in [0,32): sub = k>>3 (edge-in-4), q = k&7 (float4 slot of the 128B row)
__global__ __launch_bounds__(256) void agg1_kernel(const float* __restrict__ x32,
                                                   const int* __restrict__ sorted,
                                                   const int* __restrict__ rowptr,
                                                   const int* __restrict__ deg,
                                                   float* __restrict__ mean1) {
    const int k = threadIdx.x & 31;
    const int sub = k >> 3;
    const int q = k & 7;
    const int node = blockIdx.x * 8 + (threadIdx.x >> 5);
    const int base = rowptr[node];
    const int n = deg[node];
    float ax = 0.0f, ay = 0.0f, az = 0.0f, aw = 0.0f;
    int i0 = 0;
    for (; i0 + 32 <= n; i0 += 32) {
        int s = sorted[base + i0 + k];
#pragma unroll
        for (int j = 0; j < 8; ++j) {
            int src = __shfl(s, j * 4 + sub, 32);
            const float4 v = *(const float4*)(x32 + src * 32 + (q << 2));
            ax += v.x; ay += v.y; az += v.z; aw += v.w;
        }
    }
    const int rem = n - i0;
    if (rem > 0) {
        int s = (k < rem) ? sorted[base + i0 + k] : 0;
#pragma unroll
        for (int j = 0; j < 8; ++j) {
            int eoff = j * 4 + sub;
            int src = __shfl(s, eoff, 32);       // all lanes active for shfl
            if (eoff < rem) {
                const float4 v = *(const float4*)(x32 + src * 32 + (q << 2));
                ax += v.x; ay += v.y; az += v.z; aw += v.w;
            }
        }
    }
    // reduce over sub (lane bits 3,4) -> every lane has full sums for channels 4q..4q+3
#pragma unroll
    for (int m = 8; m <= 16; m <<= 1) {
        ax += __shfl_xor(ax, m, 32); ay += __shfl_xor(ay, m, 32);
        az += __shfl_xor(az, m, 32); aw += __shfl_xor(aw, m, 32);
    }
    // redistribute: lane k wants channel k = element (k&3) of lane (k>>2)'s float4
    const int sl = k >> 2;
    float vx = __shfl(ax, sl, 32), vy = __shfl(ay, sl, 32);
    float vz = __shfl(az, sl, 32), vw = __shfl(aw, sl, 32);
    const int e = k & 3;
    float msum = (e == 0) ? vx : ((e == 1) ? vy : ((e == 2) ? vz : vw));
    if (k < IN_CH)
        mean1[node * IN_CH + k] = msum / fmaxf((float)n, 1.0f);
}

// ---- 6. fused layer-1 dense + y2 transform (sW2 transposed: conflict-free) ----
__global__ __launch_bounds__(256) void lin1y2_kernel(const float* __restrict__ x,
                                                     const float* __restrict__ mean1,
                                                     const float* __restrict__ W1l,
                                                     const float* __restrict__ W1r,
                                                     const float* __restrict__ b1,
                                                     const float* __restrict__ W2l,
                                                     float* __restrict__ h1,
                                                     float* __restrict__ y2) {
    __shared__ float sWl[H1C * IN_CH];
    __shared__ float sWr[H1C * IN_CH];
    __shared__ float sb[H1C];
    __shared__ float sW2t[H1C * H2C];   // transposed: [c][k] = W2l[k*64+c]
    __shared__ float sh[4 * H1C];
    const int tid = threadIdx.x;
    for (int i = tid; i < H1C * IN_CH; i += 256) { sWl[i] = W1l[i]; sWr[i] = W1r[i]; }
    for (int i = tid; i < H1C * H2C; i += 256) sW2t[i] = W2l[(i & 31) * H1C + (i >> 5)];
    if (tid < H1C) sb[tid] = b1[tid];
    __syncthreads();
    const int j = tid & 63;
    const int ln = tid >> 6;
    const int node = blockIdx.x * 4 + ln;        // N_NODES % 4 == 0: no guard
    // cooperative row loads + shfl broadcast (replaces 60 same-address loads)
    float xv = (j < IN_CH) ? x[node * IN_CH + j] : 0.0f;
    float mv = (j < IN_CH) ? mean1[node * IN_CH + j] : 0.0f;
    float acc = sb[j];
#pragma unroll
    for (int c = 0; c < IN_CH; ++c) {
        float mc = __shfl(mv, c, 64);
        float xc = __shfl(xv, c, 64);
        acc += mc * sWl[j * IN_CH + c] + xc * sWr[j * IN_CH + c];
    }
    acc = fmaxf(acc, 0.0f);
    h1[node * H1C + j] = acc;
    sh[ln * H1C + j] = acc;
    __syncthreads();
    if (tid < 128) {
        const int k = tid & 31;
        const int n2 = blockIdx.x * 4 + (tid >> 5);
        const float* hr = &sh[(tid >> 5) * H1C];
        float a = 0.0f;
#pragma unroll
        for (int c = 0; c < H1C; ++c) a += hr[c] * sW2t[c * 32 + k];
        y2[n2 * H2C + k] = a;
    }
}

// ---- 7. fused layer-2 aggregation + final head ----
// float4 y2-gather -> mean2 in regs -> h2 = relu(mean2 + b2 + h1 @ W2r.T) -> logit
__global__ __launch_bounds__(256) void aggfinal_kernel(const float* __restrict__ y2,
                                                       const int* __restrict__ sorted,
                                                       const int* __restrict__ rowptr,
                                                       const int* __restrict__ deg,
                                                       const float* __restrict__ h1,
                                                       const float* __restrict__ W2r,
                                                       const float* __restrict__ b2,
                                                       const float* __restrict__ Wout,
                                                       const float* __restrict__ bout,
                                                       float* __restrict__ out) {
    __shared__ float sWt[H1C * H2C];    // transposed: [c][k] = W2r[k*64+c]
    __shared__ float sb[H2C];
    __shared__ float sWo[H2C];
    for (int i = threadIdx.x; i < H1C * H2C; i += 256)
        sWt[i] = W2r[(i & 31) * H1C + (i >> 5)];
    if (threadIdx.x < H2C) { sb[threadIdx.x] = b2[threadIdx.x]; sWo[threadIdx.x] = Wout[threadIdx.x]; }
    __syncthreads();
    const int k = threadIdx.x & 31;
    const int sub = k >> 3;
    const int q = k & 7;
    const int node = blockIdx.x * 8 + (threadIdx.x >> 5);
    const int base = rowptr[node];
    const int n = deg[node];
    float ax = 0.0f, ay = 0.0f, az = 0.0f, aw = 0.0f;
    int i0 = 0;
    for (; i0 + 32 <= n; i0 += 32) {
        int s = sorted[base + i0 + k];
#pragma unroll
        for (int j = 0; j < 8; ++j) {
            int src = __shfl(s, j * 4 + sub, 32);
            const float4 v = *(const float4*)(y2 + src * H2C + (q << 2));
            ax += v.x; ay += v.y; az += v.z; aw += v.w;
        }
    }
    const int rem = n - i0;
    if (rem > 0) {
        int s = (k < rem) ? sorted[base + i0 + k] : 0;
#pragma unroll
        for (int j = 0; j < 8; ++j) {
            int eoff = j * 4 + sub;
            int src = __shfl(s, eoff, 32);
            if (eoff < rem) {
                const float4 v = *(const float4*)(y2 + src * H2C + (q << 2));
                ax += v.x; ay += v.y; az += v.z; aw += v.w;
            }
        }
    }
#pragma unroll
    for (int m = 8; m <= 16; m <<= 1) {
        ax += __shfl_xor(ax, m, 32); ay += __shfl_xor(ay, m, 32);
        az += __shfl_xor(az, m, 32); aw += __shfl_xor(aw, m, 32);
    }
    const int sl = k >> 2;
    float vx = __shfl(ax, sl, 32), vy = __shfl(ay, sl, 32);
    float vz = __shfl(az, sl, 32), vw = __shfl(aw, sl, 32);
    const int e = k & 3;
    float msum = (e == 0) ? vx : ((e == 1) ? vy : ((e == 2) ? vz : vw));
    float acc = sb[k] + msum / fmaxf((float)n, 1.0f);
    // h1 row: 2 coalesced loads + shfl broadcast (replaces 64 same-address loads)
    const float h0 = h1[node * H1C + k];
    const float h32 = h1[node * H1C + 32 + k];
#pragma unroll
    for (int c = 0; c < 32; ++c)
        acc += __shfl(h0, c, 32) * sWt[c * 32 + k];
#pragma unroll
    for (int c = 0; c < 32; ++c)
        acc += __shfl(h32, c, 32) * sWt[(c + 32) * 32 + k];
    float val = fmaxf(acc, 0.0f) * sWo[k];
#pragma unroll
    for (int off = 16; off > 0; off >>= 1) val += __shfl_down(val, off, 32);
    if (k == 0) out[node] = val + bout[0];
}

extern "C" void kernel_launch(void* const* d_in, const int* in_sizes, int n_in,
                              void* d_out, int out_size, void* d_ws, size_t ws_size,
                              hipStream_t stream) {
    const float* x    = (const float*)d_in[0];
    const int*   ei   = (const int*)d_in[1];
    const float* W1l  = (const float*)d_in[2];
    const float* W1r  = (const float*)d_in[3];
    const float* b1   = (const float*)d_in[4];
    const float* W2l  = (const float*)d_in[5];
    const float* W2r  = (const float*)d_in[6];
    const float* b2   = (const float*)d_in[7];
    const float* Wout = (const float*)d_in[8];
    const float* bout = (const float*)d_in[9];
    float* out = (float*)d_out;

    float* fws = (float*)d_ws;
    float* x32   = fws;                                  // N*32
    float* h1    = fws + (size_t)N_NODES * 32;           // N*64 (overlay: pairs)
    float* y2    = fws + (size_t)N_NODES * 96;           // N*32
    float* buf_m = fws + (size_t)N_NODES * 128;          // N*32 (mean1)
    unsigned long long* pairs = (unsigned long long*)h1; // ull[E] == N*64 floats
    int* iws    = (int*)(fws + (size_t)N_NODES * 160);
    int* deg    = iws;                                   // N
    int* rowptr = iws + N_NODES;                         // N
    int* gcur   = iws + 2 * N_NODES;                     // 512
    int* bsum   = iws + 2 * N_NODES + 512;               // 128
    int* boff   = iws + 2 * N_NODES + 640;               // 128
    int* sorted = iws + 2 * N_NODES + 768;               // E

    hipMemsetAsync(deg, 0, (size_t)N_NODES * sizeof(int), stream);

    const int GA = (N_EDGES + CHUNK - 1) / CHUNK;  // 447

    histpad_kernel<<<N_EDGES / 256, 256, 0, stream>>>(ei, x, deg, x32);
    scanA_kernel<<<SCAN_B, 1024, 0, stream>>>(deg, rowptr, bsum);
    scanB_kernel<<<1, 128, 0, stream>>>(bsum, boff);
    scanC_kernel<<<SCAN_B, 1024, 0, stream>>>(rowptr, boff, gcur);
    binA_kernel<<<GA, 512, 0, stream>>>(ei, gcur, pairs);
    binB_kernel<<<NBUK, 512, 0, stream>>>(pairs, rowptr, sorted);
    agg1_kernel<<<N_NODES / 8, 256, 0, stream>>>(x32, sorted, rowptr, deg, buf_m);
    lin1y2_kernel<<<N_NODES / 4, 256, 0, stream>>>(x, buf_m, W1l, W1r, b1, W2l, h1, y2);
    aggfinal_kernel<<<N_NODES / 8, 256, 0, stream>>>(y2, sorted, rowptr, deg, h1,
                                                     W2r, b2, Wout, bout, out);
}

// Round 11
// 533.186 us; speedup vs baseline: 2.1509x; 1.0595x over previous
//
#include <hip/hip_runtime.h>

#define N_NODES 100000
#define N_EDGES 3200000
#define IN_CH 30
#define H1C 64
#define H2C 32

#define NBUK 391          // ceil(N_NODES / 256): bucket = dst >> 8
#define CHUNK 7168        // edges per binA block (stage = 56 KB LDS)
#define SCAN_B 98         // ceil(N_NODES / 1024) scan blocks

// ---------------- Workspace layout (floats) ----------------
//  x32    [0,      3.2M)   x padded to stride 32 (zeros in ch 30,31)
//  h1     [3.2M,   9.6M)   layer-1 output  -- OVERLAID with pairs (ull[E]) which
//                          dies in binB before h1 is born in lin1y2
//  y2     [9.6M,  12.8M)   h1 @ W2l.T
//  buf_m  [12.8M, 16.0M)   mean1 (stride 30)
//  ints at 16.0M: deg[N], rowptr[N], gcur[512], bsum[128], boff[128], sorted[E]

// ---- 1. fused: degree histogram + pad x to stride-32 ----
__global__ __launch_bounds__(256) void histpad_kernel(const int* __restrict__ ei,
                                                      const float* __restrict__ x,
                                                      int* __restrict__ deg,
                                                      float* __restrict__ x32) {
    int i = blockIdx.x * 256 + threadIdx.x;      // exactly N_EDGES threads
    atomicAdd(&deg[ei[N_EDGES + i]], 1);
    int node = i >> 5, c = i & 31;               // N_NODES*32 == N_EDGES
    x32[i] = (c < IN_CH) ? x[node * IN_CH + c] : 0.0f;
}

// ---- 2a. per-block scan: local-exclusive rowptr + block sums ----
__global__ __launch_bounds__(1024) void scanA_kernel(const int* __restrict__ deg,
                                                     int* __restrict__ rowptr,
                                                     int* __restrict__ bsum) {
    __shared__ int wsum[16];
    const int t = threadIdx.x;
    const int i = blockIdx.x * 1024 + t;
    const int lane = t & 63;
    const int wid = t >> 6;
    int v = (i < N_NODES) ? deg[i] : 0;
    int run = v;                                  // inclusive wave scan
#pragma unroll
    for (int off = 1; off < 64; off <<= 1) {
        int u = __shfl_up(run, off, 64);
        if (lane >= off) run += u;
    }
    if (lane == 63) wsum[wid] = run;
    __syncthreads();
    if (t < 16) {                                 // scan the 16 wave sums
        int w = wsum[t];
        int r2 = w;
#pragma unroll
        for (int off = 1; off < 16; off <<= 1) {
            int u = __shfl_up(r2, off, 16);
            if (t >= off) r2 += u;
        }
        wsum[t] = r2 - w;                         // exclusive
        if (t == 15) bsum[blockIdx.x] = r2;       // block total
    }
    __syncthreads();
    if (i < N_NODES) rowptr[i] = run - v + wsum[wid];
}

// ---- 2b. scan the 98 block sums (exclusive) ----
__global__ __launch_bounds__(128) void scanB_kernel(const int* __restrict__ bsum,
                                                    int* __restrict__ boff) {
    __shared__ int ws[2];
    const int t = threadIdx.x;
    int v = (t < SCAN_B) ? bsum[t] : 0;
    int run = v;
#pragma unroll
    for (int off = 1; off < 64; off <<= 1) {
        int u = __shfl_up(run, off, 64);
        if ((t & 63) >= off) run += u;
    }
    if ((t & 63) == 63) ws[t >> 6] = run;
    __syncthreads();
    int excl = run - v + ((t >= 64) ? ws[0] : 0);
    if (t < SCAN_B) boff[t] = excl;
}

// ---- 2c. add block offsets; init binA bucket cursors from final rowptr ----
__global__ __launch_bounds__(1024) void scanC_kernel(int* __restrict__ rowptr,
                                                     const int* __restrict__ boff,
                                                     int* __restrict__ gcur) {
    const int i = blockIdx.x * 1024 + threadIdx.x;
    if (i < N_NODES) {
        int r = rowptr[i] + boff[blockIdx.x];
        rowptr[i] = r;
        if ((i & 255) == 0) gcur[i >> 8] = r;
    }
}

// ---- 3. pass A: LDS-binned write of (dst,src) pairs, grouped by bucket ----
__global__ __launch_bounds__(512) void binA_kernel(const int* __restrict__ ei,
                                                   int* __restrict__ gcur,
                                                   unsigned long long* __restrict__ pairs) {
    __shared__ int hist[392];
    __shared__ int lbase[392];
    __shared__ int gbase[392];
    __shared__ int hcnt[392];
    __shared__ unsigned long long stage[CHUNK];
    const int tid = threadIdx.x;
    const int e0 = blockIdx.x * CHUNK;
    const int n = min(CHUNK, N_EDGES - e0);
    for (int i = tid; i < 392; i += 512) { hist[i] = 0; hcnt[i] = 0; }
    __syncthreads();
    for (int i = tid; i < n; i += 512)
        atomicAdd(&hist[ei[N_EDGES + e0 + i] >> 8], 1);
    __syncthreads();
    if (tid < 64) {  // wave-0 strip scan: 64 lanes x 7 buckets
        int base = tid * 7, v[7], s = 0;
#pragma unroll
        for (int k = 0; k < 7; ++k) {
            int idx = base + k;
            v[k] = (idx < NBUK) ? hist[idx] : 0;
            s += v[k];
        }
        int run = s;
#pragma unroll
        for (int off = 1; off < 64; off <<= 1) {
            int t2 = __shfl_up(run, off, 64);
            if (tid >= off) run += t2;
        }
        int excl = run - s;
#pragma unroll
        for (int k = 0; k < 7; ++k) {
            int idx = base + k;
            if (idx < NBUK) lbase[idx] = excl;
            excl += v[k];
        }
    }
    __syncthreads();
    for (int b = tid; b < NBUK; b += 512) {
        int h = hist[b];
        if (h > 0) gbase[b] = atomicAdd(&gcur[b], h);
    }
    __syncthreads();
    for (int i = tid; i < n; i += 512) {
        int s = ei[e0 + i];
        int d = ei[N_EDGES + e0 + i];
        int b = d >> 8;
        int p = lbase[b] + atomicAdd(&hcnt[b], 1);
        stage[p] = ((unsigned long long)(unsigned)d << 32) | (unsigned)s;
    }
    __syncthreads();
    for (int i = tid; i < n; i += 512) {
        unsigned long long v = stage[i];
        int d = (int)(v >> 32);
        int b = d >> 8;
        pairs[gbase[b] + (i - lbase[b])] = v;   // ~144B coalesced runs
    }
}

// ---- 4. pass B: per-bucket LDS-cursor scatter into final CSR order ----
__global__ __launch_bounds__(512) void binB_kernel(const unsigned long long* __restrict__ pairs,
                                                   const int* __restrict__ rowptr,
                                                   int* __restrict__ sorted) {
    __shared__ int cur[256];
    const int tid = threadIdx.x;
    const int dstbase = blockIdx.x << 8;
    if (tid < 256) {
        int d = dstbase + tid;
        cur[tid] = (d < N_NODES) ? rowptr[d] : 0;
    }
    __syncthreads();
    const int lo = rowptr[dstbase];
    const int hi = (dstbase + 256 < N_NODES) ? rowptr[dstbase + 256] : N_EDGES;
    for (int i = lo + tid; i < hi; i += 512) {
        unsigned long long v = pairs[i];
        int d = (int)(v >> 32);
        int s = (int)(v & 0xffffffffULL);
        int pos = atomicAdd(&cur[d & 255], 1);
        sorted[pos] = s;                         // writes confined to ~32KB window
    }
}

// ---- 5. layer-1 mean aggregation: float4 gather, 4 edge-rows per instruction ----
// lane k in [0,32): sub = k>>3 (edge-in-4), q = k&7 (float4 slot of the 128B row)
__global__ __launch_bounds__(256) void agg1_kernel(const float* __restrict__ x32,
                                                   const int* __restrict__ sorted,
                                                   const int* __restrict__ rowptr,
                                                   const int* __restrict__ deg,
                                                   float* __restrict__ mean1) {
    const int k = threadIdx.x & 31;
    const int sub = k >> 3;
    const int q = k & 7;
    const int node = blockIdx.x * 8 + (threadIdx.x >> 5);
    const int base = rowptr[node];
    const int n = deg[node];
    float ax = 0.0f, ay = 0.0f, az = 0.0f, aw = 0.0f;
    int i0 = 0;
    for (; i0 + 32 <= n; i0 += 32) {
        int s = sorted[base + i0 + k];
#pragma unroll
        for (int j = 0; j < 8; ++j) {
            int src = __shfl(s, j * 4 + sub, 32);
            const float4 v = *(const float4*)(x32 + src * 32 + (q << 2));
            ax += v.x; ay += v.y; az += v.z; aw += v.w;
        }
    }
    const int rem = n - i0;
    if (rem > 0) {
        int s = (k < rem) ? sorted[base + i0 + k] : 0;
#pragma unroll
        for (int j = 0; j < 8; ++j) {
            int eoff = j * 4 + sub;
            int src = __shfl(s, eoff, 32);       // all lanes active for shfl
            if (eoff < rem) {
                const float4 v = *(const float4*)(x32 + src * 32 + (q << 2));
                ax += v.x; ay += v.y; az += v.z; aw += v.w;
            }
        }
    }
    // reduce over sub (lane bits 3,4) -> every lane has full sums for channels 4q..4q+3
#pragma unroll
    for (int m = 8; m <= 16; m <<= 1) {
        ax += __shfl_xor(ax, m, 32); ay += __shfl_xor(ay, m, 32);
        az += __shfl_xor(az, m, 32); aw += __shfl_xor(aw, m, 32);
    }
    // redistribute: lane k wants channel k = element (k&3) of lane (k>>2)'s float4
    const int sl = k >> 2;
    float vx = __shfl(ax, sl, 32), vy = __shfl(ay, sl, 32);
    float vz = __shfl(az, sl, 32), vw = __shfl(aw, sl, 32);
    const int e = k & 3;
    float msum = (e == 0) ? vx : ((e == 1) ? vy : ((e == 2) ? vz : vw));
    if (k < IN_CH)
        mean1[node * IN_CH + k] = msum / fmaxf((float)n, 1.0f);
}

// ---- 6. fused layer-1 dense + y2 transform: 32 nodes/block (8x staging amortization) ----
// Phase 1 (8 rounds x 4 nodes): h1 = relu(mean1 @ W1l.T + b1 + x @ W1r.T) -> global + sh
// Phase 2 (all 256 threads):    y2 = sh @ W2l.T
__global__ __launch_bounds__(256) void lin1y2_kernel(const float* __restrict__ x,
                                                     const float* __restrict__ mean1,
                                                     const float* __restrict__ W1l,
                                                     const float* __restrict__ W1r,
                                                     const float* __restrict__ b1,
                                                     const float* __restrict__ W2l,
                                                     float* __restrict__ h1,
                                                     float* __restrict__ y2) {
    __shared__ float sWl[H1C * IN_CH];
    __shared__ float sWr[H1C * IN_CH];
    __shared__ float sb[H1C];
    __shared__ float sW2t[H1C * H2C];   // transposed: [c][k] = W2l[k*64+c]
    __shared__ float sh[32 * H1C];      // h1 for 32 nodes
    const int tid = threadIdx.x;
    for (int i = tid; i < H1C * IN_CH; i += 256) { sWl[i] = W1l[i]; sWr[i] = W1r[i]; }
    for (int i = tid; i < H1C * H2C; i += 256) sW2t[i] = W2l[(i & 31) * H1C + (i >> 5)];
    if (tid < H1C) sb[tid] = b1[tid];
    __syncthreads();
    const int j = tid & 63;
    const int ln = tid >> 6;
    const int nbase = blockIdx.x * 32;           // N_NODES % 32 == 0: no guard
#pragma unroll
    for (int r = 0; r < 8; ++r) {
        const int nl = r * 4 + ln;
        const int node = nbase + nl;
        float xv = (j < IN_CH) ? x[node * IN_CH + j] : 0.0f;
        float mv = (j < IN_CH) ? mean1[node * IN_CH + j] : 0.0f;
        float acc = sb[j];
#pragma unroll
        for (int c = 0; c < IN_CH; ++c) {
            float mc = __shfl(mv, c, 64);
            float xc = __shfl(xv, c, 64);
            acc += mc * sWl[j * IN_CH + c] + xc * sWr[j * IN_CH + c];
        }
        acc = fmaxf(acc, 0.0f);
        h1[node * H1C + j] = acc;
        sh[nl * H1C + j] = acc;                  // each thread owns its slot
    }
    __syncthreads();
#pragma unroll
    for (int r = 0; r < 4; ++r) {                // 32 nodes x 32 ch = 1024 outputs
        const int o = r * 256 + tid;
        const int nl = o >> 5;
        const int k = o & 31;
        const float* hr = &sh[nl * H1C];
        float a = 0.0f;
#pragma unroll
        for (int c = 0; c < H1C; ++c) a += hr[c] * sW2t[c * 32 + k];
        y2[(nbase + nl) * H2C + k] = a;
    }
}

// ---- 7. fused layer-2 aggregation + final head ----
// float4 y2-gather -> mean2 in regs -> h2 = relu(mean2 + b2 + h1 @ W2r.T) -> logit
__global__ __launch_bounds__(256) void aggfinal_kernel(const float* __restrict__ y2,
                                                       const int* __restrict__ sorted,
                                                       const int* __restrict__ rowptr,
                                                       const int* __restrict__ deg,
                                                       const float* __restrict__ h1,
                                                       const float* __restrict__ W2r,
                                                       const float* __restrict__ b2,
                                                       const float* __restrict__ Wout,
                                                       const float* __restrict__ bout,
                                                       float* __restrict__ out) {
    __shared__ float sWt[H1C * H2C];    // transposed: [c][k] = W2r[k*64+c]
    __shared__ float sb[H2C];
    __shared__ float sWo[H2C];
    for (int i = threadIdx.x; i < H1C * H2C; i += 256)
        sWt[i] = W2r[(i & 31) * H1C + (i >> 5)];
    if (threadIdx.x < H2C) { sb[threadIdx.x] = b2[threadIdx.x]; sWo[threadIdx.x] = Wout[threadIdx.x]; }
    __syncthreads();
    const int k = threadIdx.x & 31;
    const int sub = k >> 3;
    const int q = k & 7;
    const int node = blockIdx.x * 8 + (threadIdx.x >> 5);
    const int base = rowptr[node];
    const int n = deg[node];
    float ax = 0.0f, ay = 0.0f, az = 0.0f, aw = 0.0f;
    int i0 = 0;
    for (; i0 + 32 <= n; i0 += 32) {
        int s = sorted[base + i0 + k];
#pragma unroll
        for (int j = 0; j < 8; ++j) {
            int src = __shfl(s, j * 4 + sub, 32);
            const float4 v = *(const float4*)(y2 + src * H2C + (q << 2));
            ax += v.x; ay += v.y; az += v.z; aw += v.w;
        }
    }
    const int rem = n - i0;
    if (rem > 0) {
        int s = (k < rem) ? sorted[base + i0 + k] : 0;
#pragma unroll
        for (int j = 0; j < 8; ++j) {
            int eoff = j * 4 + sub;
            int src = __shfl(s, eoff, 32);
            if (eoff < rem) {
                const float4 v = *(const float4*)(y2 + src * H2C + (q << 2));
                ax += v.x; ay += v.y; az += v.z; aw += v.w;
            }
        }
    }
#pragma unroll
    for (int m = 8; m <= 16; m <<= 1) {
        ax += __shfl_xor(ax, m, 32); ay += __shfl_xor(ay, m, 32);
        az += __shfl_xor(az, m, 32); aw += __shfl_xor(aw, m, 32);
    }
    const int sl = k >> 2;
    float vx = __shfl(ax, sl, 32), vy = __shfl(ay, sl, 32);
    float vz = __shfl(az, sl, 32), vw = __shfl(aw, sl, 32);
    const int e = k & 3;
    float msum = (e == 0) ? vx : ((e == 1) ? vy : ((e == 2) ? vz : vw));
    float acc = sb[k] + msum / fmaxf((float)n, 1.0f);
    // h1 row: 2 coalesced loads + shfl broadcast (replaces 64 same-address loads)
    const float h0 = h1[node * H1C + k];
    const float h32 = h1[node * H1C + 32 + k];
#pragma unroll
    for (int c = 0; c < 32; ++c)
        acc += __shfl(h0, c, 32) * sWt[c * 32 + k];
#pragma unroll
    for (int c = 0; c < 32; ++c)
        acc += __shfl(h32, c, 32) * sWt[(c + 32) * 32 + k];
    float val = fmaxf(acc, 0.0f) * sWo[k];
#pragma unroll
    for (int off = 16; off > 0; off >>= 1) val += __shfl_down(val, off, 32);
    if (k == 0) out[node] = val + bout[0];
}

extern "C" void kernel_launch(void* const* d_in, const int* in_sizes, int n_in,
                              void* d_out, int out_size, void* d_ws, size_t ws_size,
                              hipStream_t stream) {
    const float* x    = (const float*)d_in[0];
    const int*   ei   = (const int*)d_in[1];
    const float* W1l  = (const float*)d_in[2];
    const float* W1r  = (const float*)d_in[3];
    const float* b1   = (const float*)d_in[4];
    const float* W2l  = (const float*)d_in[5];
    const float* W2r  = (const float*)d_in[6];
    const float* b2   = (const float*)d_in[7];
    const float* Wout = (const float*)d_in[8];
    const float* bout = (const float*)d_in[9];
    float* out = (float*)d_out;

    float* fws = (float*)d_ws;
    float* x32   = fws;                                  // N*32
    float* h1    = fws + (size_t)N_NODES * 32;           // N*64 (overlay: pairs)
    float* y2    = fws + (size_t)N_NODES * 96;           // N*32
    float* buf_m = fws + (size_t)N_NODES * 128;          // N*32 (mean1)
    unsigned long long* pairs = (unsigned long long*)h1; // ull[E] == N*64 floats
    int* iws    = (int*)(fws + (size_t)N_NODES * 160);
    int* deg    = iws;                                   // N
    int* rowptr = iws + N_NODES;                         // N
    int* gcur   = iws + 2 * N_NODES;                     // 512
    int* bsum   = iws + 2 * N_NODES + 512;               // 128
    int* boff   = iws + 2 * N_NODES + 640;               // 128
    int* sorted = iws + 2 * N_NODES + 768;               // E

    hipMemsetAsync(deg, 0, (size_t)N_NODES * sizeof(int), stream);

    const int GA = (N_EDGES + CHUNK - 1) / CHUNK;  // 447

    histpad_kernel<<<N_EDGES / 256, 256, 0, stream>>>(ei, x, deg, x32);
    scanA_kernel<<<SCAN_B, 1024, 0, stream>>>(deg, rowptr, bsum);
    scanB_kernel<<<1, 128, 0, stream>>>(bsum, boff);
    scanC_kernel<<<SCAN_B, 1024, 0, stream>>>(rowptr, boff, gcur);
    binA_kernel<<<GA, 512, 0, stream>>>(ei, gcur, pairs);
    binB_kernel<<<NBUK, 512, 0, stream>>>(pairs, rowptr, sorted);
    agg1_kernel<<<N_NODES / 8, 256, 0, stream>>>(x32, sorted, rowptr, deg, buf_m);
    lin1y2_kernel<<<N_NODES / 32, 256, 0, stream>>>(x, buf_m, W1l, W1r, b1, W2l, h1, y2);
    aggfinal_kernel<<<N_NODES / 8, 256, 0, stream>>>(y2, sorted, rowptr, deg, h1,
                                                     W2r, b2, Wout, bout, out);
}

// Round 12
// 424.005 us; speedup vs baseline: 2.7048x; 1.2575x over previous
//
#include <hip/hip_runtime.h>

#define N_NODES 100000
#define N_EDGES 3200000
#define IN_CH 30
#define H1C 64
#define H2C 32

#define NBUK 391          // ceil(N_NODES / 256): bucket = dst >> 8
#define CHUNK 7168        // edges per binA/bhist block
#define GA 447            // ceil(N_EDGES / CHUNK)

// ---------------- Workspace layout (floats) ----------------
//  x32    [0,      3.2M)   x padded to stride 32 (zeros in ch 30,31)
//  h1     [3.2M,   9.6M)   layer-1 output -- OVERLAID with pairs (ull[E]), which
//                          dies in binB2 before h1 is born in lin1y2
//  y2     [9.6M,  12.8M)   h1 @ W2l.T
//  buf_m  [12.8M, 16.0M)   mean1 (stride 30)
//  ints: deg[N], rowptr[N], gcur[392], gbuk[392], gbase0[392], sorted[E]

// ---- 1. fused: bucket histogram (LDS-preaggregated) + pad x to stride-32 ----
__global__ __launch_bounds__(512) void bhistpad_kernel(const int* __restrict__ ei,
                                                       const float* __restrict__ x,
                                                       int* __restrict__ gbuk,
                                                       float* __restrict__ x32) {
    __shared__ int gh[392];
    const int tid = threadIdx.x;
    for (int i = tid; i < 392; i += 512) gh[i] = 0;
    __syncthreads();
    const int e0 = blockIdx.x * CHUNK;
    const int n = min(CHUNK, N_EDGES - e0);
    for (int i = tid; i < n; i += 512)
        atomicAdd(&gh[ei[N_EDGES + e0 + i] >> 8], 1);
    // pad x -> x32 (grid-stride; disjoint from hist index space)
    const int stride = gridDim.x * 512;
    for (int i = blockIdx.x * 512 + tid; i < N_EDGES; i += stride) {
        int node = i >> 5, c = i & 31;               // N_NODES*32 == N_EDGES
        x32[i] = (c < IN_CH) ? x[node * IN_CH + c] : 0.0f;
    }
    __syncthreads();
    for (int b = tid; b < NBUK; b += 512) {
        int h = gh[b];
        if (h > 0) atomicAdd(&gbuk[b], h);           // <=391 atomics/block
    }
}

// ---- 2. scan 391 bucket counts -> bucket bases (gcur mutable, gbase0 + sentinel) ----
__global__ __launch_bounds__(512) void bscan_kernel(const int* __restrict__ gbuk,
                                                    int* __restrict__ gcur,
                                                    int* __restrict__ gbase0) {
    __shared__ int ws8[8];
    const int t = threadIdx.x;
    const int lane = t & 63;
    const int wid = t >> 6;
    int v = (t < NBUK) ? gbuk[t] : 0;
    int run = v;
#pragma unroll
    for (int off = 1; off < 64; off <<= 1) {
        int u = __shfl_up(run, off, 64);
        if (lane >= off) run += u;
    }
    if (lane == 63) ws8[wid] = run;
    __syncthreads();
    if (t < 8) {
        int w = ws8[t];
        int r2 = w;
#pragma unroll
        for (int off = 1; off < 8; off <<= 1) {
            int u = __shfl_up(r2, off, 8);
            if (t >= off) r2 += u;
        }
        ws8[t] = r2 - w;
    }
    __syncthreads();
    int excl = run - v + ws8[wid];
    if (t <= NBUK) {                                  // t==NBUK: sentinel = N_EDGES
        gcur[t] = excl;
        gbase0[t] = excl;
    }
}

// ---- 3. pass A: LDS-binned write of (dst,src) pairs, grouped by bucket ----
__global__ __launch_bounds__(512) void binA_kernel(const int* __restrict__ ei,
                                                   int* __restrict__ gcur,
                                                   unsigned long long* __restrict__ pairs) {
    __shared__ int hist[392];
    __shared__ int lbase[392];
    __shared__ int gbase[392];
    __shared__ int hcnt[392];
    __shared__ unsigned long long stage[CHUNK];
    const int tid = threadIdx.x;
    const int e0 = blockIdx.x * CHUNK;
    const int n = min(CHUNK, N_EDGES - e0);
    for (int i = tid; i < 392; i += 512) { hist[i] = 0; hcnt[i] = 0; }
    __syncthreads();
    for (int i = tid; i < n; i += 512)
        atomicAdd(&hist[ei[N_EDGES + e0 + i] >> 8], 1);
    __syncthreads();
    if (tid < 64) {  // wave-0 strip scan: 64 lanes x 7 buckets
        int base = tid * 7, v[7], s = 0;
#pragma unroll
        for (int k = 0; k < 7; ++k) {
            int idx = base + k;
            v[k] = (idx < NBUK) ? hist[idx] : 0;
            s += v[k];
        }
        int run = s;
#pragma unroll
        for (int off = 1; off < 64; off <<= 1) {
            int t2 = __shfl_up(run, off, 64);
            if (tid >= off) run += t2;
        }
        int excl = run - s;
#pragma unroll
        for (int k = 0; k < 7; ++k) {
            int idx = base + k;
            if (idx < NBUK) lbase[idx] = excl;
            excl += v[k];
        }
    }
    __syncthreads();
    for (int b = tid; b < NBUK; b += 512) {
        int h = hist[b];
        if (h > 0) gbase[b] = atomicAdd(&gcur[b], h);
    }
    __syncthreads();
    for (int i = tid; i < n; i += 512) {
        int s = ei[e0 + i];
        int d = ei[N_EDGES + e0 + i];
        int b = d >> 8;
        int p = lbase[b] + atomicAdd(&hcnt[b], 1);
        stage[p] = ((unsigned long long)(unsigned)d << 32) | (unsigned)s;
    }
    __syncthreads();
    for (int i = tid; i < n; i += 512) {
        unsigned long long v = stage[i];
        int d = (int)(v >> 32);
        int b = d >> 8;
        pairs[gbase[b] + (i - lbase[b])] = v;   // ~144B coalesced runs
    }
}

// ---- 4. pass B: per-bucket deg/rowptr derivation + CSR scatter ----
__global__ __launch_bounds__(512) void binB2_kernel(const unsigned long long* __restrict__ pairs,
                                                    const int* __restrict__ gbase0,
                                                    int* __restrict__ rowptr,
                                                    int* __restrict__ deg,
                                                    int* __restrict__ sorted) {
    __shared__ int hcnt[256];
    __shared__ int cur[256];
    __shared__ int ws4[4];
    const int t = threadIdx.x;
    const int b = blockIdx.x;
    for (int i = t; i < 256; i += 512) hcnt[i] = 0;
    __syncthreads();
    const int lo = gbase0[b];
    const int hi = gbase0[b + 1];
    for (int i = lo + t; i < hi; i += 512)
        atomicAdd(&hcnt[(int)(pairs[i] >> 32) & 255], 1);
    __syncthreads();
    int v = 0, run = 0;
    if (t < 256) {
        v = hcnt[t];
        run = v;
        const int lane = t & 63;
#pragma unroll
        for (int off = 1; off < 64; off <<= 1) {
            int u = __shfl_up(run, off, 64);
            if (lane >= off) run += u;
        }
        if (lane == 63) ws4[t >> 6] = run;
    }
    __syncthreads();
    if (t < 4) {
        int w = ws4[t];
        int r2 = w;
#pragma unroll
        for (int off = 1; off < 4; off <<= 1) {
            int u = __shfl_up(r2, off, 4);
            if (t >= off) r2 += u;
        }
        ws4[t] = r2 - w;
    }
    __syncthreads();
    if (t < 256) {
        int g = lo + (run - v + ws4[t >> 6]);
        cur[t] = g;
        int node = (b << 8) + t;
        if (node < N_NODES) { rowptr[node] = g; deg[node] = v; }
    }
    __syncthreads();
    for (int i = lo + t; i < hi; i += 512) {
        unsigned long long pv = pairs[i];
        int d = (int)(pv >> 32);
        int s = (int)(pv & 0xffffffffULL);
        int pos = atomicAdd(&cur[d & 255], 1);
        sorted[pos] = s;                         // writes confined to ~32KB window
    }
}

// ---- 5. layer-1 mean aggregation: float4 gather, 4 edge-rows per instruction ----
__global__ __launch_bounds__(256) void agg1_kernel(const float* __restrict__ x32,
                                                   const int* __restrict__ sorted,
                                                   const int* __restrict__ rowptr,
                                                   const int* __restrict__ deg,
                                                   float* __restrict__ mean1) {
    const int k = threadIdx.x & 31;
    const int sub = k >> 3;
    const int q = k & 7;
    const int node = blockIdx.x * 8 + (threadIdx.x >> 5);
    const int base = rowptr[node];
    const int n = deg[node];
    float ax = 0.0f, ay = 0.0f, az = 0.0f, aw = 0.0f;
    int i0 = 0;
    for (; i0 + 32 <= n; i0 += 32) {
        int s = sorted[base + i0 + k];
#pragma unroll
        for (int j = 0; j < 8; ++j) {
            int src = __shfl(s, j * 4 + sub, 32);
            const float4 v = *(const float4*)(x32 + src * 32 + (q << 2));
            ax += v.x; ay += v.y; az += v.z; aw += v.w;
        }
    }
    const int rem = n - i0;
    if (rem > 0) {
        int s = (k < rem) ? sorted[base + i0 + k] : 0;
#pragma unroll
        for (int j = 0; j < 8; ++j) {
            int eoff = j * 4 + sub;
            int src = __shfl(s, eoff, 32);
            if (eoff < rem) {
                const float4 v = *(const float4*)(x32 + src * 32 + (q << 2));
                ax += v.x; ay += v.y; az += v.z; aw += v.w;
            }
        }
    }
#pragma unroll
    for (int m = 8; m <= 16; m <<= 1) {
        ax += __shfl_xor(ax, m, 32); ay += __shfl_xor(ay, m, 32);
        az += __shfl_xor(az, m, 32); aw += __shfl_xor(aw, m, 32);
    }
    const int sl = k >> 2;
    float vx = __shfl(ax, sl, 32), vy = __shfl(ay, sl, 32);
    float vz = __shfl(az, sl, 32), vw = __shfl(aw, sl, 32);
    const int e = k & 3;
    float msum = (e == 0) ? vx : ((e == 1) ? vy : ((e == 2) ? vz : vw));
    if (k < IN_CH)
        mean1[node * IN_CH + k] = msum / fmaxf((float)n, 1.0f);
}

// ---- 6. fused layer-1 dense + y2 transform: 32 nodes/block ----
__global__ __launch_bounds__(256) void lin1y2_kernel(const float* __restrict__ x,
                                                     const float* __restrict__ mean1,
                                                     const float* __restrict__ W1l,
                                                     const float* __restrict__ W1r,
                                                     const float* __restrict__ b1,
                                                     const float* __restrict__ W2l,
                                                     float* __restrict__ h1,
                                                     float* __restrict__ y2) {
    __shared__ float sWl[H1C * IN_CH];
    __shared__ float sWr[H1C * IN_CH];
    __shared__ float sb[H1C];
    __shared__ float sW2t[H1C * H2C];   // transposed: [c][k] = W2l[k*64+c]
    __shared__ float sh[32 * H1C];      // h1 for 32 nodes
    const int tid = threadIdx.x;
    for (int i = tid; i < H1C * IN_CH; i += 256) { sWl[i] = W1l[i]; sWr[i] = W1r[i]; }
    for (int i = tid; i < H1C * H2C; i += 256) sW2t[i] = W2l[(i & 31) * H1C + (i >> 5)];
    if (tid < H1C) sb[tid] = b1[tid];
    __syncthreads();
    const int j = tid & 63;
    const int ln = tid >> 6;
    const int nbase = blockIdx.x * 32;           // N_NODES % 32 == 0: no guard
#pragma unroll
    for (int r = 0; r < 8; ++r) {
        const int nl = r * 4 + ln;
        const int node = nbase + nl;
        float xv = (j < IN_CH) ? x[node * IN_CH + j] : 0.0f;
        float mv = (j < IN_CH) ? mean1[node * IN_CH + j] : 0.0f;
        float acc = sb[j];
#pragma unroll
        for (int c = 0; c < IN_CH; ++c) {
            float mc = __shfl(mv, c, 64);
            float xc = __shfl(xv, c, 64);
            acc += mc * sWl[j * IN_CH + c] + xc * sWr[j * IN_CH + c];
        }
        acc = fmaxf(acc, 0.0f);
        h1[node * H1C + j] = acc;
        sh[nl * H1C + j] = acc;                  // each thread owns its slot
    }
    __syncthreads();
#pragma unroll
    for (int r = 0; r < 4; ++r) {                // 32 nodes x 32 ch = 1024 outputs
        const int o = r * 256 + tid;
        const int nl = o >> 5;
        const int k = o & 31;
        const float* hr = &sh[nl * H1C];
        float a = 0.0f;
#pragma unroll
        for (int c = 0; c < H1C; ++c) a += hr[c] * sW2t[c * 32 + k];
        y2[(nbase + nl) * H2C + k] = a;
    }
}

// ---- 7. fused layer-2 aggregation + final head ----
__global__ __launch_bounds__(256) void aggfinal_kernel(const float* __restrict__ y2,
                                                       const int* __restrict__ sorted,
                                                       const int* __restrict__ rowptr,
                                                       const int* __restrict__ deg,
                                                       const float* __restrict__ h1,
                                                       const float* __restrict__ W2r,
                                                       const float* __restrict__ b2,
                                                       const float* __restrict__ Wout,
                                                       const float* __restrict__ bout,
                                                       float* __restrict__ out) {
    __shared__ float sWt[H1C * H2C];    // transposed: [c][k] = W2r[k*64+c]
    __shared__ float sb[H2C];
    __shared__ float sWo[H2C];
    for (int i = threadIdx.x; i < H1C * H2C; i += 256)
        sWt[i] = W2r[(i & 31) * H1C + (i >> 5)];
    if (threadIdx.x < H2C) { sb[threadIdx.x] = b2[threadIdx.x]; sWo[threadIdx.x] = Wout[threadIdx.x]; }
    __syncthreads();
    const int k = threadIdx.x & 31;
    const int sub = k >> 3;
    const int q = k & 7;
    const int node = blockIdx.x * 8 + (threadIdx.x >> 5);
    const int base = rowptr[node];
    const int n = deg[node];
    float ax = 0.0f, ay = 0.0f, az = 0.0f, aw = 0.0f;
    int i0 = 0;
    for (; i0 + 32 <= n; i0 += 32) {
        int s = sorted[base + i0 + k];
#pragma unroll
        for (int j = 0; j < 8; ++j) {
            int src = __shfl(s, j * 4 + sub, 32);
            const float4 v = *(const float4*)(y2 + src * H2C + (q << 2));
            ax += v.x; ay += v.y; az += v.z; aw += v.w;
        }
    }
    const int rem = n - i0;
    if (rem > 0) {
        int s = (k < rem) ? sorted[base + i0 + k] : 0;
#pragma unroll
        for (int j = 0; j < 8; ++j) {
            int eoff = j * 4 + sub;
            int src = __shfl(s, eoff, 32);
            if (eoff < rem) {
                const float4 v = *(const float4*)(y2 + src * H2C + (q << 2));
                ax += v.x; ay += v.y; az += v.z; aw += v.w;
            }
        }
    }
#pragma unroll
    for (int m = 8; m <= 16; m <<= 1) {
        ax += __shfl_xor(ax, m, 32); ay += __shfl_xor(ay, m, 32);
        az += __shfl_xor(az, m, 32); aw += __shfl_xor(aw, m, 32);
    }
    const int sl = k >> 2;
    float vx = __shfl(ax, sl, 32), vy = __shfl(ay, sl, 32);
    float vz = __shfl(az, sl, 32), vw = __shfl(aw, sl, 32);
    const int e = k & 3;
    float msum = (e == 0) ? vx : ((e == 1) ? vy : ((e == 2) ? vz : vw));
    float acc = sb[k] + msum / fmaxf((float)n, 1.0f);
    const float h0 = h1[node * H1C + k];
    const float h32 = h1[node * H1C + 32 + k];
#pragma unroll
    for (int c = 0; c < 32; ++c)
        acc += __shfl(h0, c, 32) * sWt[c * 32 + k];
#pragma unroll
    for (int c = 0; c < 32; ++c)
        acc += __shfl(h32, c, 32) * sWt[(c + 32) * 32 + k];
    float val = fmaxf(acc, 0.0f) * sWo[k];
#pragma unroll
    for (int off = 16; off > 0; off >>= 1) val += __shfl_down(val, off, 32);
    if (k == 0) out[node] = val + bout[0];
}

extern "C" void kernel_launch(void* const* d_in, const int* in_sizes, int n_in,
                              void* d_out, int out_size, void* d_ws, size_t ws_size,
                              hipStream_t stream) {
    const float* x    = (const float*)d_in[0];
    const int*   ei   = (const int*)d_in[1];
    const float* W1l  = (const float*)d_in[2];
    const float* W1r  = (const float*)d_in[3];
    const float* b1   = (const float*)d_in[4];
    const float* W2l  = (const float*)d_in[5];
    const float* W2r  = (const float*)d_in[6];
    const float* b2   = (const float*)d_in[7];
    const float* Wout = (const float*)d_in[8];
    const float* bout = (const float*)d_in[9];
    float* out = (float*)d_out;

    float* fws = (float*)d_ws;
    float* x32   = fws;                                  // N*32
    float* h1    = fws + (size_t)N_NODES * 32;           // N*64 (overlay: pairs)
    float* y2    = fws + (size_t)N_NODES * 96;           // N*32
    float* buf_m = fws + (size_t)N_NODES * 128;          // N*32 (mean1)
    unsigned long long* pairs = (unsigned long long*)h1; // ull[E] == N*64 floats
    int* iws    = (int*)(fws + (size_t)N_NODES * 160);
    int* deg    = iws;                                   // N
    int* rowptr = iws + N_NODES;                         // N
    int* gcur   = iws + 2 * N_NODES;                     // 392
    int* gbuk   = iws + 2 * N_NODES + 392;               // 392
    int* gbase0 = iws + 2 * N_NODES + 784;               // 392
    int* sorted = iws + 2 * N_NODES + 1176;              // E

    hipMemsetAsync(gbuk, 0, 392 * sizeof(int), stream);

    bhistpad_kernel<<<GA, 512, 0, stream>>>(ei, x, gbuk, x32);
    bscan_kernel<<<1, 512, 0, stream>>>(gbuk, gcur, gbase0);
    binA_kernel<<<GA, 512, 0, stream>>>(ei, gcur, pairs);
    binB2_kernel<<<NBUK, 512, 0, stream>>>(pairs, gbase0, rowptr, deg, sorted);
    agg1_kernel<<<N_NODES / 8, 256, 0, stream>>>(x32, sorted, rowptr, deg, buf_m);
    lin1y2_kernel<<<N_NODES / 32, 256, 0, stream>>>(x, buf_m, W1l, W1r, b1, W2l, h1, y2);
    aggfinal_kernel<<<N_NODES / 8, 256, 0, stream>>>(y2, sorted, rowptr, deg, h1,
                                                     W2r, b2, Wout, bout, out);
}

// Round 15
// 362.050 us; speedup vs baseline: 3.1676x; 1.1711x over previous
//
#include <hip/hip_runtime.h>

#define N_NODES 100000
#define N_EDGES 3200000
#define IN_CH 30
#define H1C 64
#define H2C 32

#define NBUK 391          // ceil(N_NODES / 256): bucket = dst >> 8
#define CHUNK 7168        // edges per binA/bhist block
#define GA 447            // ceil(N_EDGES / CHUNK)

// ---------------- Workspace layout (floats) ----------------
//  x32    [0,      3.2M)   x padded to stride 32 (zeros in ch 30,31)
//  h1     [3.2M,   9.6M)   layer-1 output -- OVERLAID with pairs (ull[E]), which
//                          dies in binB2 before h1 is born in lin1y2
//  y2     [9.6M,  12.8M)   h1 @ W2l.T
//  buf_m  [12.8M, 16.0M)   mean1 (stride 32, ch 30/31 zeroed)
//  ints: deg[N], rowptr[N], gcur[392], gbuk[392], gbase0[392], sorted[E]

// ---- 1. fused: bucket histogram (LDS-preaggregated) + pad x to stride-32 ----
__global__ __launch_bounds__(512) void bhistpad_kernel(const int* __restrict__ ei,
                                                       const float* __restrict__ x,
                                                       int* __restrict__ gbuk,
                                                       float* __restrict__ x32) {
    __shared__ int gh[392];
    const int tid = threadIdx.x;
    for (int i = tid; i < 392; i += 512) gh[i] = 0;
    __syncthreads();
    const int e0 = blockIdx.x * CHUNK;
    const int n = min(CHUNK, N_EDGES - e0);
    for (int i = tid; i < n; i += 512)
        atomicAdd(&gh[ei[N_EDGES + e0 + i] >> 8], 1);
    // pad x -> x32 (grid-stride; disjoint from hist index space)
    const int stride = gridDim.x * 512;
    for (int i = blockIdx.x * 512 + tid; i < N_EDGES; i += stride) {
        int node = i >> 5, c = i & 31;               // N_NODES*32 == N_EDGES
        x32[i] = (c < IN_CH) ? x[node * IN_CH + c] : 0.0f;
    }
    __syncthreads();
    for (int b = tid; b < NBUK; b += 512) {
        int h = gh[b];
        if (h > 0) atomicAdd(&gbuk[b], h);           // <=391 atomics/block
    }
}

// ---- 2. scan 391 bucket counts -> bucket bases (gcur mutable, gbase0 + sentinel) ----
__global__ __launch_bounds__(512) void bscan_kernel(const int* __restrict__ gbuk,
                                                    int* __restrict__ gcur,
                                                    int* __restrict__ gbase0) {
    __shared__ int ws8[8];
    const int t = threadIdx.x;
    const int lane = t & 63;
    const int wid = t >> 6;
    int v = (t < NBUK) ? gbuk[t] : 0;
    int run = v;
#pragma unroll
    for (int off = 1; off < 64; off <<= 1) {
        int u = __shfl_up(run, off, 64);
        if (lane >= off) run += u;
    }
    if (lane == 63) ws8[wid] = run;
    __syncthreads();
    if (t < 8) {
        int w = ws8[t];
        int r2 = w;
#pragma unroll
        for (int off = 1; off < 8; off <<= 1) {
            int u = __shfl_up(r2, off, 8);
            if (t >= off) r2 += u;
        }
        ws8[t] = r2 - w;
    }
    __syncthreads();
    int excl = run - v + ws8[wid];
    if (t <= NBUK) {                                  // t==NBUK: sentinel = N_EDGES
        gcur[t] = excl;
        gbase0[t] = excl;
    }
}

// ---- 3. pass A: LDS-binned write of (dst,src) pairs, grouped by bucket ----
__global__ __launch_bounds__(512) void binA_kernel(const int* __restrict__ ei,
                                                   int* __restrict__ gcur,
                                                   unsigned long long* __restrict__ pairs) {
    __shared__ int hist[392];
    __shared__ int lbase[392];
    __shared__ int gbase[392];
    __shared__ int hcnt[392];
    __shared__ unsigned long long stage[CHUNK];
    const int tid = threadIdx.x;
    const int e0 = blockIdx.x * CHUNK;
    const int n = min(CHUNK, N_EDGES - e0);
    for (int i = tid; i < 392; i += 512) { hist[i] = 0; hcnt[i] = 0; }
    __syncthreads();
    for (int i = tid; i < n; i += 512)
        atomicAdd(&hist[ei[N_EDGES + e0 + i] >> 8], 1);
    __syncthreads();
    if (tid < 64) {  // wave-0 strip scan: 64 lanes x 7 buckets
        int base = tid * 7, v[7], s = 0;
#pragma unroll
        for (int k = 0; k < 7; ++k) {
            int idx = base + k;
            v[k] = (idx < NBUK) ? hist[idx] : 0;
            s += v[k];
        }
        int run = s;
#pragma unroll
        for (int off = 1; off < 64; off <<= 1) {
            int t2 = __shfl_up(run, off, 64);
            if (tid >= off) run += t2;
        }
        int excl = run - s;
#pragma unroll
        for (int k = 0; k < 7; ++k) {
            int idx = base + k;
            if (idx < NBUK) lbase[idx] = excl;
            excl += v[k];
        }
    }
    __syncthreads();
    for (int b = tid; b < NBUK; b += 512) {
        int h = hist[b];
        if (h > 0) gbase[b] = atomicAdd(&gcur[b], h);
    }
    __syncthreads();
    for (int i = tid; i < n; i += 512) {
        int s = ei[e0 + i];
        int d = ei[N_EDGES + e0 + i];
        int b = d >> 8;
        int p = lbase[b] + atomicAdd(&hcnt[b], 1);
        stage[p] = ((unsigned long long)(unsigned)d << 32) | (unsigned)s;
    }
    __syncthreads();
    for (int i = tid; i < n; i += 512) {
        unsigned long long v = stage[i];
        int d = (int)(v >> 32);
        int b = d >> 8;
        pairs[gbase[b] + (i - lbase[b])] = v;   // ~144B coalesced runs
    }
}

// ---- 4. pass B: per-bucket deg/rowptr derivation + CSR scatter ----
__global__ __launch_bounds__(512) void binB2_kernel(const unsigned long long* __restrict__ pairs,
                                                    const int* __restrict__ gbase0,
                                                    int* __restrict__ rowptr,
                                                    int* __restrict__ deg,
                                                    int* __restrict__ sorted) {
    __shared__ int hcnt[256];
    __shared__ int cur[256];
    __shared__ int ws4[4];
    const int t = threadIdx.x;
    const int b = blockIdx.x;
    for (int i = t; i < 256; i += 512) hcnt[i] = 0;
    __syncthreads();
    const int lo = gbase0[b];
    const int hi = gbase0[b + 1];
    for (int i = lo + t; i < hi; i += 512)
        atomicAdd(&hcnt[(int)(pairs[i] >> 32) & 255], 1);
    __syncthreads();
    int v = 0, run = 0;
    if (t < 256) {
        v = hcnt[t];
        run = v;
        const int lane = t & 63;
#pragma unroll
        for (int off = 1; off < 64; off <<= 1) {
            int u = __shfl_up(run, off, 64);
            if (lane >= off) run += u;
        }
        if (lane == 63) ws4[t >> 6] = run;
    }
    __syncthreads();
    if (t < 4) {
        int w = ws4[t];
        int r2 = w;
#pragma unroll
        for (int off = 1; off < 4; off <<= 1) {
            int u = __shfl_up(r2, off, 4);
            if (t >= off) r2 += u;
        }
        ws4[t] = r2 - w;
    }
    __syncthreads();
    if (t < 256) {
        int g = lo + (run - v + ws4[t >> 6]);
        cur[t] = g;
        int node = (b << 8) + t;
        if (node < N_NODES) { rowptr[node] = g; deg[node] = v; }
    }
    __syncthreads();
    for (int i = lo + t; i < hi; i += 512) {
        unsigned long long pv = pairs[i];
        int d = (int)(pv >> 32);
        int s = (int)(pv & 0xffffffffULL);
        int pos = atomicAdd(&cur[d & 255], 1);
        sorted[pos] = s;                         // writes confined to ~32KB window
    }
}

// ---- 5. layer-1 mean aggregation: float4 gather; mean1 written stride-32, zero-padded ----
__global__ __launch_bounds__(256) void agg1_kernel(const float* __restrict__ x32,
                                                   const int* __restrict__ sorted,
                                                   const int* __restrict__ rowptr,
                                                   const int* __restrict__ deg,
                                                   float* __restrict__ mean1) {
    const int k = threadIdx.x & 31;
    const int sub = k >> 3;
    const int q = k & 7;
    const int node = blockIdx.x * 8 + (threadIdx.x >> 5);
    const int base = rowptr[node];
    const int n = deg[node];
    float ax = 0.0f, ay = 0.0f, az = 0.0f, aw = 0.0f;
    int i0 = 0;
    for (; i0 + 32 <= n; i0 += 32) {
        int s = sorted[base + i0 + k];
#pragma unroll
        for (int j = 0; j < 8; ++j) {
            int src = __shfl(s, j * 4 + sub, 32);
            const float4 v = *(const float4*)(x32 + src * 32 + (q << 2));
            ax += v.x; ay += v.y; az += v.z; aw += v.w;
        }
    }
    const int rem = n - i0;
    if (rem > 0) {
        int s = (k < rem) ? sorted[base + i0 + k] : 0;
#pragma unroll
        for (int j = 0; j < 8; ++j) {
            int eoff = j * 4 + sub;
            int src = __shfl(s, eoff, 32);
            if (eoff < rem) {
                const float4 v = *(const float4*)(x32 + src * 32 + (q << 2));
                ax += v.x; ay += v.y; az += v.z; aw += v.w;
            }
        }
    }
#pragma unroll
    for (int m = 8; m <= 16; m <<= 1) {
        ax += __shfl_xor(ax, m, 32); ay += __shfl_xor(ay, m, 32);
        az += __shfl_xor(az, m, 32); aw += __shfl_xor(aw, m, 32);
    }
    const int sl = k >> 2;
    float vx = __shfl(ax, sl, 32), vy = __shfl(ay, sl, 32);
    float vz = __shfl(az, sl, 32), vw = __shfl(aw, sl, 32);
    const int e = k & 3;
    float msum = (e == 0) ? vx : ((e == 1) ? vy : ((e == 2) ? vz : vw));
    // stride-32 write, ch 30/31 = 0 (enables float4 staging downstream)
    mean1[node * 32 + k] = (k < IN_CH) ? msum / fmaxf((float)n, 1.0f) : 0.0f;
}

// ---- 6. fused layer-1 dense + y2: weights in REGISTERS, uniform float4 LDS reads ----
// Phase 1: wave = 1 node/round; sx4/sm4 reads are uniform-address broadcasts (no conflict).
// Phase 2: W2l row k in 16 float4 regs; sh rows read as broadcast float4.
__global__ __launch_bounds__(256) void lin1y2_kernel(const float* __restrict__ x32,
                                                     const float* __restrict__ mean1,
                                                     const float* __restrict__ W1l,
                                                     const float* __restrict__ W1r,
                                                     const float* __restrict__ b1,
                                                     const float* __restrict__ W2l,
                                                     float* __restrict__ h1,
                                                     float* __restrict__ y2) {
    __shared__ float sx[32 * 32];
    __shared__ float sm[32 * 32];
    __shared__ float sh[32 * H1C];
    const int tid = threadIdx.x;
    const int nbase = blockIdx.x * 32;           // N_NODES % 32 == 0
    // stage activations: linear float4 copies (1 instr/thread each)
    ((float4*)sx)[tid] = ((const float4*)(x32 + (size_t)nbase * 32))[tid];
    ((float4*)sm)[tid] = ((const float4*)(mean1 + (size_t)nbase * 32))[tid];
    const int j = tid & 63;
    const int ln = tid >> 6;
    // W1 rows j -> registers (static-indexed; L1-hot across 3125 blocks)
    float wl[32], wr[32];
#pragma unroll
    for (int c = 0; c < 32; ++c) {
        wl[c] = (c < IN_CH) ? W1l[j * IN_CH + c] : 0.0f;
        wr[c] = (c < IN_CH) ? W1r[j * IN_CH + c] : 0.0f;
    }
    const float bj = b1[j];
    __syncthreads();
#pragma unroll
    for (int r = 0; r < 8; ++r) {
        const int nl = r * 4 + ln;               // whole wave shares this node
        const float4* sx4 = (const float4*)(sx + nl * 32);
        const float4* sm4 = (const float4*)(sm + nl * 32);
        float acc = bj;
#pragma unroll
        for (int q = 0; q < 8; ++q) {
            float4 xv = sx4[q];                  // uniform addr -> broadcast
            float4 mv = sm4[q];
            acc += mv.x * wl[4 * q + 0] + xv.x * wr[4 * q + 0];
            acc += mv.y * wl[4 * q + 1] + xv.y * wr[4 * q + 1];
            acc += mv.z * wl[4 * q + 2] + xv.z * wr[4 * q + 2];
            acc += mv.w * wl[4 * q + 3] + xv.w * wr[4 * q + 3];
        }
        acc = fmaxf(acc, 0.0f);
        h1[(nbase + nl) * H1C + j] = acc;
        sh[nl * H1C + j] = acc;                  // each thread owns its slot
    }
    // W2l row k -> registers (k fixed per thread)
    float4 w2[16];
    {
        const float4* w2row = (const float4*)(W2l + (tid & 31) * H1C);
#pragma unroll
        for (int q = 0; q < 16; ++q) w2[q] = w2row[q];
    }
    __syncthreads();
#pragma unroll
    for (int r = 0; r < 4; ++r) {                // 32 nodes x 32 ch = 1024 outputs
        const int nl = r * 8 + (tid >> 5);
        const float4* shrow = (const float4*)(sh + nl * H1C);
        float a = 0.0f;
#pragma unroll
        for (int q = 0; q < 16; ++q) {
            float4 h4 = shrow[q];                // 2 distinct addrs/wave -> broadcast
            a += h4.x * w2[q].x + h4.y * w2[q].y + h4.z * w2[q].z + h4.w * w2[q].w;
        }
        y2[(nbase + nl) * H2C + (tid & 31)] = a;
    }
}

// ---- 7. fused layer-2 aggregation + final head ----
__global__ __launch_bounds__(256) void aggfinal_kernel(const float* __restrict__ y2,
                                                       const int* __restrict__ sorted,
                                                       const int* __restrict__ rowptr,
                                                       const int* __restrict__ deg,
                                                       const float* __restrict__ h1,
                                                       const float* __restrict__ W2r,
                                                       const float* __restrict__ b2,
                                                       const float* __restrict__ Wout,
                                                       const float* __restrict__ bout,
                                                       float* __restrict__ out) {
    __shared__ float sWt[H1C * H2C];    // transposed: [c][k] = W2r[k*64+c]
    __shared__ float sb[H2C];
    __shared__ float sWo[H2C];
    for (int i = threadIdx.x; i < H1C * H2C; i += 256)
        sWt[i] = W2r[(i & 31) * H1C + (i >> 5)];
    if (threadIdx.x < H2C) { sb[threadIdx.x] = b2[threadIdx.x]; sWo[threadIdx.x] = Wout[threadIdx.x]; }
    __syncthreads();
    const int k = threadIdx.x & 31;
    const int sub = k >> 3;
    const int q = k & 7;
    const int node = blockIdx.x * 8 + (threadIdx.x >> 5);
    const int base = rowptr[node];
    const int n = deg[node];
    float ax = 0.0f, ay = 0.0f, az = 0.0f, aw = 0.0f;
    int i0 = 0;
    for (; i0 + 32 <= n; i0 += 32) {
        int s = sorted[base + i0 + k];
#pragma unroll
        for (int j = 0; j < 8; ++j) {
            int src = __shfl(s, j * 4 + sub, 32);
            const float4 v = *(const float4*)(y2 + src * H2C + (q << 2));
            ax += v.x; ay += v.y; az += v.z; aw += v.w;
        }
    }
    const int rem = n - i0;
    if (rem > 0) {
        int s = (k < rem) ? sorted[base + i0 + k] : 0;
#pragma unroll
        for (int j = 0; j < 8; ++j) {
            int eoff = j * 4 + sub;
            int src = __shfl(s, eoff, 32);
            if (eoff < rem) {
                const float4 v = *(const float4*)(y2 + src * H2C + (q << 2));
                ax += v.x; ay += v.y; az += v.z; aw += v.w;
            }
        }
    }
#pragma unroll
    for (int m = 8; m <= 16; m <<= 1) {
        ax += __shfl_xor(ax, m, 32); ay += __shfl_xor(ay, m, 32);
        az += __shfl_xor(az, m, 32); aw += __shfl_xor(aw, m, 32);
    }
    const int sl = k >> 2;
    float vx = __shfl(ax, sl, 32), vy = __shfl(ay, sl, 32);
    float vz = __shfl(az, sl, 32), vw = __shfl(aw, sl, 32);
    const int e = k & 3;
    float msum = (e == 0) ? vx : ((e == 1) ? vy : ((e == 2) ? vz : vw));
    float acc = sb[k] + msum / fmaxf((float)n, 1.0f);
    const float h0 = h1[node * H1C + k];
    const float h32 = h1[node * H1C + 32 + k];
#pragma unroll
    for (int c = 0; c < 32; ++c)
        acc += __shfl(h0, c, 32) * sWt[c * 32 + k];
#pragma unroll
    for (int c = 0; c < 32; ++c)
        acc += __shfl(h32, c, 32) * sWt[(c + 32) * 32 + k];
    float val = fmaxf(acc, 0.0f) * sWo[k];
#pragma unroll
    for (int off = 16; off > 0; off >>= 1) val += __shfl_down(val, off, 32);
    if (k == 0) out[node] = val + bout[0];
}

extern "C" void kernel_launch(void* const* d_in, const int* in_sizes, int n_in,
                              void* d_out, int out_size, void* d_ws, size_t ws_size,
                              hipStream_t stream) {
    const float* x    = (const float*)d_in[0];
    const int*   ei   = (const int*)d_in[1];
    const float* W1l  = (const float*)d_in[2];
    const float* W1r  = (const float*)d_in[3];
    const float* b1   = (const float*)d_in[4];
    const float* W2l  = (const float*)d_in[5];
    const float* W2r  = (const float*)d_in[6];
    const float* b2   = (const float*)d_in[7];
    const float* Wout = (const float*)d_in[8];
    const float* bout = (const float*)d_in[9];
    float* out = (float*)d_out;

    float* fws = (float*)d_ws;
    float* x32   = fws;                                  // N*32
    float* h1    = fws + (size_t)N_NODES * 32;           // N*64 (overlay: pairs)
    float* y2    = fws + (size_t)N_NODES * 96;           // N*32
    float* buf_m = fws + (size_t)N_NODES * 128;          // N*32 (mean1, stride 32)
    unsigned long long* pairs = (unsigned long long*)h1; // ull[E] == N*64 floats
    int* iws    = (int*)(fws + (size_t)N_NODES * 160);
    int* deg    = iws;                                   // N
    int* rowptr = iws + N_NODES;                         // N
    int* gcur   = iws + 2 * N_NODES;                     // 392
    int* gbuk   = iws + 2 * N_NODES + 392;               // 392
    int* gbase0 = iws + 2 * N_NODES + 784;               // 392
    int* sorted = iws + 2 * N_NODES + 1176;              // E

    hipMemsetAsync(gbuk, 0, 392 * sizeof(int), stream);

    bhistpad_kernel<<<GA, 512, 0, stream>>>(ei, x, gbuk, x32);
    bscan_kernel<<<1, 512, 0, stream>>>(gbuk, gcur, gbase0);
    binA_kernel<<<GA, 512, 0, stream>>>(ei, gcur, pairs);
    binB2_kernel<<<NBUK, 512, 0, stream>>>(pairs, gbase0, rowptr, deg, sorted);
    agg1_kernel<<<N_NODES / 8, 256, 0, stream>>>(x32, sorted, rowptr, deg, buf_m);
    lin1y2_kernel<<<N_NODES / 32, 256, 0, stream>>>(x32, buf_m, W1l, W1r, b1, W2l, h1, y2);
    aggfinal_kernel<<<N_NODES / 8, 256, 0, stream>>>(y2, sorted, rowptr, deg, h1,
                                                     W2r, b2, Wout, bout, out);
}